// Round 11
// baseline (1303.113 us; speedup 1.0000x reference)
//
#include <hip/hip_runtime.h>

// Problem constants: B=4096, K=16, H=32, HM=128, STEPS=8
#define OFF_MS  524288
#define OFF_CS  557056
#define OFF_IP  1081344
#define OFF_CUM 1179648
#define OFF_EPS 1183744

#define HSTR 136   // padded bf16 row stride (272B = 68dw -> 2-way banks, free)
#define BSTR 40    // padded bf16 row stride (80B = 20dw)

struct Params {
  const float *knn, *query, *fw1, *fb1, *fw2, *fb2, *fw3, *fb3, *qkv_w,
    *ptp_w1, *ptp_b1, *ptp_w2, *ptp_b2, *pta_w1, *pta_b1, *pta_w2, *pta_b2,
    *caq_w, *caq_b, *cak_w, *cak_b, *cav_w, *cav_b,
    *cap_w1, *cap_b1, *cap_w2, *cap_b2, *caa_w1, *caa_b1, *caa_w2, *caa_b2,
    *im_w1, *im_b1, *im_w2, *im_b2, *im_w3, *im_b3,
    *ep_w1, *ep_b1, *ep_w2, *ep_b2, *ep_w3, *ep_b3;
  float *o_ld, *o_ms, *o_cs, *o_ip, *o_cum, *o_eps;
};
static_assert(sizeof(Params) == 49 * sizeof(void*), "Params layout");

typedef float f32x4 __attribute__((ext_vector_type(4)));
typedef unsigned short u16x8 __attribute__((ext_vector_type(8)));

__device__ __forceinline__ unsigned short f2b(float x) {  // fp32->bf16 RNE
  unsigned u = __float_as_uint(x);
  u += 0x7fffu + ((u >> 16) & 1u);
  return (unsigned short)(u >> 16);
}
__device__ __forceinline__ unsigned pack2(float lo, float hi) {
  return (unsigned)f2b(lo) | ((unsigned)f2b(hi) << 16);
}

#define MFMA(acc, a, bb) \
  asm volatile("s_nop 2\n\tv_mfma_f32_16x16x32_bf16 %0, %1, %2, %0" \
               : "+v"(acc) : "v"(a), "v"(bb))
#define MFMA_FENCE(acc) asm volatile("s_nop 7\n\ts_nop 7" : "+v"(acc))

// DUAL-BATCH: each block handles batches b0=2*blk, b0+1. Phases A-C run
// per-batch sequentially (full 256 threads); phase D runs both batches
// concurrently -- waves {0,1} = batch0, {2,3} = batch1 -- so the serial
// qq/secE chains execute 2-at-a-time and each barrier serves 2 batches.
// s_uD is time-shared: q|k during phase C, kk|vvb for phase D.
// (256,2): the only no-spill config on this toolchain (rounds 2/3/6/8).
__launch_bounds__(256, 2)
__global__ void puray_kernel(Params p) {
  const int b0 = blockIdx.x * 2;
  const int t = threadIdx.x;
  const int w = t >> 6, l = t & 63;
  const int ln16 = l & 15, kg = l >> 4, k0 = kg * 8;
  const int g = w >> 1, pw = w & 1;   // phase-D pair id / wave-in-pair

  __shared__ __align__(16) unsigned short s_wTA[32 * HSTR];  // ptp_w2T -> cap_w2T [n][k]
  __shared__ __align__(16) unsigned short s_wTB[128 * BSTR]; // pta_w1T -> caa_w1T [n][k]
  __shared__ __align__(16) unsigned short s_wTC[32 * HSTR];  // pta_w2T -> caa_w2T [n][k]
  __shared__ __align__(16) unsigned short s_hidb[32 * HSTR]; // C: 32 rows; D: [g][16]
  __shared__ __align__(16) unsigned short s_simb[32 * BSTR];
  __shared__ float s_rpe[32 * 33];
  __shared__ float s_sim[32 * 33];
  __shared__ float s_v[512], s_feats[512];
  __shared__ float s_uD[2048];        // [g]: C-time q|k, D-time kk|vvb
  __shared__ float s_coords2[96], s_relv2[96], s_reld2[32];
  __shared__ float s_qry2[6], s_op2[6], s_cum2[2], s_qq2[64];

  // ---- stage ptp/pta weights (shared by both batches) + per-batch scalars ----
#pragma unroll 4
  for (int m = 0; m < 16; ++m) {
    const int idx = t + 256 * m;
    { const int n = idx >> 7, k = idx & 127;
      s_wTA[n * HSTR + k] = f2b(p.ptp_w2[k * 32 + n]);
      s_wTC[n * HSTR + k] = f2b(p.pta_w2[k * 32 + n]); }
    { const int n = idx >> 5, k = idx & 31;
      s_wTB[n * BSTR + k] = f2b(p.pta_w1[k * 128 + n]); }
  }
  if (t < 96) s_coords2[t] = p.knn[b0 * 48 + t];
  else if (t < 102) s_qry2[t - 96] = p.query[b0 * 3 + (t - 96)];
  else if (t < 104) s_cum2[t - 102] = 0.f;
  else if (t < 110) s_op2[t - 104] = 0.f;
  __syncthreads();

  // ================= Phases A/B/C per batch (sequential) =================
  for (int gg = 0; gg < 2; ++gg) {
    const float* cg = s_coords2 + gg * 48;
    float* uq = s_uD + gg * 1024;   // q | k during this batch's C

    // ---- Phase A ----
#pragma unroll
    for (int m = 0; m < 2; ++m) {
      const int l2 = t + 256 * m, pp = l2 >> 5, jj = l2 & 31;
      float a = p.fb1[jj];
#pragma unroll
      for (int c = 0; c < 3; ++c) a = fmaf(cg[pp * 3 + c], p.fw1[c * 32 + jj], a);
      s_rpe[l2] = fmaxf(a, 0.f);
    }
    __syncthreads();
#pragma unroll
    for (int m = 0; m < 2; ++m) {
      const int l2 = t + 256 * m, pp = l2 >> 5, jj = l2 & 31;
      float a = p.fb2[jj];
      for (int i = 0; i < 32; ++i) a = fmaf(s_rpe[pp * 32 + i], p.fw2[i * 32 + jj], a);
      s_sim[l2] = fmaxf(a, 0.f);
    }
    __syncthreads();
#pragma unroll
    for (int m = 0; m < 2; ++m) {
      const int l2 = t + 256 * m, pp = l2 >> 5, jj = l2 & 31;
      float a = p.fb3[jj];
      for (int i = 0; i < 32; ++i) a = fmaf(s_sim[pp * 32 + i], p.fw3[i * 32 + jj], a);
      s_feats[l2] = a;
    }
    __syncthreads();

    // ---- Phase B: qkv ----
#pragma unroll
    for (int m = 0; m < 6; ++m) {
      const int l2 = t + 256 * m, pp = l2 / 96, o = l2 % 96;
      float a = 0.f;
      for (int i = 0; i < 32; ++i) a = fmaf(s_feats[pp * 32 + i], p.qkv_w[i * 96 + o], a);
      if (o < 32) uq[pp * 32 + o] = a;
      else if (o < 64) uq[512 + pp * 32 + o - 32] = a;
      else s_v[pp * 32 + o - 64] = a;
    }
    __syncthreads();

    // ---- Phase C ----
    for (int ig = 0; ig < 16; ig += 2) {
      {  // sec1a: hv[32][128]
        const int r = t >> 3;
        const int i = ig + (r >> 4), j = r & 15;
        const float r0 = cg[i * 3 + 0] - cg[j * 3 + 0];
        const float r1 = cg[i * 3 + 1] - cg[j * 3 + 1];
        const float r2 = cg[i * 3 + 2] - cg[j * 3 + 2];
        const int d0 = (t & 7) * 16;
#pragma unroll
        for (int x = 0; x < 16; x += 2) {
          const int d = d0 + x;
          const float h0v = fmaxf(fmaf(r0, p.ptp_w1[d],
                             fmaf(r1, p.ptp_w1[128 + d],
                             fmaf(r2, p.ptp_w1[256 + d], p.ptp_b1[d]))), 0.f);
          const float h1v = fmaxf(fmaf(r0, p.ptp_w1[d + 1],
                             fmaf(r1, p.ptp_w1[128 + d + 1],
                             fmaf(r2, p.ptp_w1[256 + d + 1], p.ptp_b1[d + 1]))), 0.f);
          ((unsigned*)s_hidb)[(r * HSTR + d) >> 1] = pack2(h0v, h1v);
        }
      }
      __syncthreads();
      {  // G1: rpe = hv @ ptp_w2 + b2; simin -> s_simb
        const int mb = w >> 1, nb = w & 1, n = nb * 16 + ln16;
        const float bias = p.ptp_b2[n];
        f32x4 acc = {bias, bias, bias, bias};
#pragma unroll
        for (int kk = 0; kk < 4; ++kk) {
          const u16x8 a = *(const u16x8*)&s_hidb[(mb * 16 + ln16) * HSTR + kk * 32 + k0];
          const u16x8 bb = *(const u16x8*)&s_wTA[n * HSTR + kk * 32 + k0];
          MFMA(acc, a, bb);
        }
        MFMA_FENCE(acc);
#pragma unroll
        for (int r2 = 0; r2 < 4; ++r2) {
          const int row = mb * 16 + kg * 4 + r2;
          const float val = acc[r2];
          s_rpe[row * 33 + n] = val;
          const int i = ig + (row >> 4), j = row & 15;
          s_simb[row * BSTR + n] = f2b(uq[i * 32 + n] - uq[512 + j * 32 + n] + val);
        }
      }
      __syncthreads();
      {  // G2: hid = relu(simin @ pta_w1 + b1)
        const int mb = w & 1;
        const u16x8 a = *(const u16x8*)&s_simb[(mb * 16 + ln16) * BSTR + k0];
#pragma unroll
        for (int j2 = 0; j2 < 4; ++j2) {
          const int n = ((w >> 1) * 4 + j2) * 16 + ln16;
          const u16x8 bb = *(const u16x8*)&s_wTB[n * BSTR + k0];
          const float bias = p.pta_b1[n];
          f32x4 acc = {bias, bias, bias, bias};
          MFMA(acc, a, bb);
          MFMA_FENCE(acc);
#pragma unroll
          for (int r2 = 0; r2 < 4; ++r2)
            s_hidb[(mb * 16 + kg * 4 + r2) * HSTR + n] = f2b(fmaxf(acc[r2], 0.f));
        }
      }
      __syncthreads();
      {  // G3: sim = hid @ pta_w2 + b2 -> s_sim (fp32)
        const int mb = w >> 1, nb = w & 1, n = nb * 16 + ln16;
        const float bias = p.pta_b2[n];
        f32x4 acc = {bias, bias, bias, bias};
#pragma unroll
        for (int kk = 0; kk < 4; ++kk) {
          const u16x8 a = *(const u16x8*)&s_hidb[(mb * 16 + ln16) * HSTR + kk * 32 + k0];
          const u16x8 bb = *(const u16x8*)&s_wTC[n * HSTR + kk * 32 + k0];
          MFMA(acc, a, bb);
        }
        MFMA_FENCE(acc);
#pragma unroll
        for (int r2 = 0; r2 < 4; ++r2) s_sim[(mb * 16 + kg * 4 + r2) * 33 + n] = acc[r2];
      }
      __syncthreads();
      if (t < 64) {  // sec4: softmax + weighted sum
        const int g2 = t >> 5, h = t & 31;
        float mx = -1e30f;
#pragma unroll
        for (int j2 = 0; j2 < 16; ++j2) mx = fmaxf(mx, s_sim[(g2 * 16 + j2) * 33 + h]);
        float sum = 0.f, o = 0.f;
#pragma unroll
        for (int j2 = 0; j2 < 16; ++j2) {
          const float e = __expf(s_sim[(g2 * 16 + j2) * 33 + h] - mx);
          sum += e;
          o = fmaf(e, s_v[j2 * 32 + h] + s_rpe[(g2 * 16 + j2) * 33 + h], o);
        }
        s_feats[(ig + g2) * 32 + h] = o / sum;
      }
      __syncthreads();
    }

    // ---- kk/vvb for this batch (overwrites q|k region) ----
#pragma unroll
    for (int m = 0; m < 2; ++m) {
      const int l2 = t + 256 * m, k = l2 >> 5, h = l2 & 31;
      float akk = p.cak_b[h], avv = p.cav_b[h];
      for (int i = 0; i < 32; ++i) {
        const float f = s_feats[k * 32 + i];
        akk = fmaf(f, p.cak_w[i * 32 + h], akk);
        avv = fmaf(f, p.cav_w[i * 32 + h], avv);
      }
      uq[k * 32 + h] = akk;
      uq[512 + k * 32 + h] = avv;
    }
    __syncthreads();
  }

  // ---- restage weights for cross-attention ----
#pragma unroll 4
  for (int m = 0; m < 16; ++m) {
    const int idx = t + 256 * m;
    { const int n = idx >> 7, k = idx & 127;
      s_wTA[n * HSTR + k] = f2b(p.cap_w2[k * 32 + n]);
      s_wTC[n * HSTR + k] = f2b(p.caa_w2[k * 32 + n]); }
    { const int n = idx >> 5, k = idx & 31;
      s_wTB[n * BSTR + k] = f2b(p.caa_w1[k * 128 + n]); }
  }
  __syncthreads();

  // ================= Phase D: both batches concurrently =================
  const float* cg = s_coords2 + g * 48;
  const float* uD = s_uD + g * 1024;  // kk | vvb for this pair's batch
  const int bD = b0 + g;
  for (int s = 0; s <= 8; ++s) {
    float rv0 = 0.f, rv1 = 0.f, rv2 = 0.f;
    if (pw == 1) {  // secA: hv[16][128] for batch g (wave pw1)
      const int k = l >> 2, dseg = (l & 3) * 32;
      float c0, c1, c2;
      if (s < 8) {
        c0 = cg[k * 3 + 0] - s_op2[g * 3 + 0];
        c1 = cg[k * 3 + 1] - s_op2[g * 3 + 1];
        c2 = cg[k * 3 + 2] - s_op2[g * 3 + 2];
      } else {
        const float rd = s_reld2[g * 16 + k];
        c0 = s_relv2[g * 48 + k * 3 + 0] * rd;
        c1 = s_relv2[g * 48 + k * 3 + 1] * rd;
        c2 = s_relv2[g * 48 + k * 3 + 2] * rd;
      }
#pragma unroll 4
      for (int x = 0; x < 32; x += 2) {
        const int d = dseg + x;
        const float h0v = fmaxf(fmaf(c0, p.cap_w1[d],
                           fmaf(c1, p.cap_w1[128 + d],
                           fmaf(c2, p.cap_w1[256 + d], p.cap_b1[d]))), 0.f);
        const float h1v = fmaxf(fmaf(c0, p.cap_w1[d + 1],
                           fmaf(c1, p.cap_w1[128 + d + 1],
                           fmaf(c2, p.cap_w1[256 + d + 1], p.cap_b1[d + 1]))), 0.f);
        ((unsigned*)s_hidb)[((g * 16 + k) * HSTR + d) >> 1] = pack2(h0v, h1v);
      }
    } else {  // pw0: rel/o_ld + qq chain for batch g
      const int h = l & 31;
      if (s < 8 && l < 16) {
        const float r0 = cg[l * 3 + 0] - s_op2[g * 3 + 0];
        const float r1 = cg[l * 3 + 1] - s_op2[g * 3 + 1];
        const float r2 = cg[l * 3 + 2] - s_op2[g * 3 + 2];
        const float rd = sqrtf(r0 * r0 + r1 * r1 + r2 * r2);
        const float inv = 1.f / rd;
        rv0 = r0 * inv; rv1 = r1 * inv; rv2 = r2 * inv;
        s_reld2[g * 16 + l] = rd;
        s_relv2[g * 48 + l * 3 + 0] = rv0;
        s_relv2[g * 48 + l * 3 + 1] = rv1;
        s_relv2[g * 48 + l * 3 + 2] = rv2;
        p.o_ld[bD * 128 + s * 16 + l] = rd;
      }
      float opc0, opc1, opc2;
      if (s < 8) {
        const float cum = s_cum2[g];
        opc0 = s_qry2[g * 3 + 0] * cum; opc1 = s_qry2[g * 3 + 1] * cum; opc2 = s_qry2[g * 3 + 2] * cum;
      } else {
        opc0 = s_op2[g * 3 + 0]; opc1 = s_op2[g * 3 + 1]; opc2 = s_op2[g * 3 + 2];
      }
      float v1 = fmaxf(fmaf(opc0, p.fw1[h],
                    fmaf(opc1, p.fw1[32 + h],
                    fmaf(opc2, p.fw1[64 + h], p.fb1[h]))), 0.f);
      float a = p.fb2[h];
      for (int i2 = 0; i2 < 32; ++i2) a = fmaf(__shfl(v1, i2), p.fw2[i2 * 32 + h], a);
      const float v2 = fmaxf(a, 0.f);
      a = p.fb3[h];
      for (int i2 = 0; i2 < 32; ++i2) a = fmaf(__shfl(v2, i2), p.fw3[i2 * 32 + h], a);
      const float opf = a;
      a = p.caq_b[h];
      for (int i2 = 0; i2 < 32; ++i2) a = fmaf(__shfl(opf, i2), p.caq_w[i2 * 32 + h], a);
      if (l < 32) s_qq2[g * 32 + h] = a;
    }
    __syncthreads();
    {  // secB: pe = hv @ cap_w2 + b2; fused ain -> s_simb (both waves of pair)
      const int n = pw * 16 + ln16;
      const float bias = p.cap_b2[n];
      f32x4 acc = {bias, bias, bias, bias};
#pragma unroll
      for (int kk = 0; kk < 4; ++kk) {
        const u16x8 a = *(const u16x8*)&s_hidb[(g * 16 + ln16) * HSTR + kk * 32 + k0];
        const u16x8 bb = *(const u16x8*)&s_wTA[n * HSTR + kk * 32 + k0];
        MFMA(acc, a, bb);
      }
      MFMA_FENCE(acc);
#pragma unroll
      for (int r2 = 0; r2 < 4; ++r2) {
        const int row = kg * 4 + r2;
        const float pe = acc[r2];
        s_rpe[(g * 16 + row) * 33 + n] = pe;
        s_simb[(g * 16 + row) * BSTR + n] = f2b(s_qq2[g * 32 + n] - uD[row * 32 + n] + pe);
      }
    }
    __syncthreads();
    {  // secC: hid = relu(ain @ caa_w1 + b1) (2 waves x 4 n-tiles per batch)
      const u16x8 a = *(const u16x8*)&s_simb[(g * 16 + ln16) * BSTR + k0];
#pragma unroll
      for (int j2 = 0; j2 < 4; ++j2) {
        const int n = (pw * 4 + j2) * 16 + ln16;
        const u16x8 bb = *(const u16x8*)&s_wTB[n * BSTR + k0];
        const float bias = p.caa_b1[n];
        f32x4 acc = {bias, bias, bias, bias};
        MFMA(acc, a, bb);
        MFMA_FENCE(acc);
#pragma unroll
        for (int r2 = 0; r2 < 4; ++r2)
          s_hidb[(g * 16 + kg * 4 + r2) * HSTR + n] = f2b(fmaxf(acc[r2], 0.f));
      }
    }
    __syncthreads();
    {  // secD: sim = hid @ caa_w2 + b2 -> s_sim (fp32)
      const int n = pw * 16 + ln16;
      const float bias = p.caa_b2[n];
      f32x4 acc = {bias, bias, bias, bias};
#pragma unroll
      for (int kk = 0; kk < 4; ++kk) {
        const u16x8 a = *(const u16x8*)&s_hidb[(g * 16 + ln16) * HSTR + kk * 32 + k0];
        const u16x8 bb = *(const u16x8*)&s_wTC[n * HSTR + kk * 32 + k0];
        MFMA(acc, a, bb);
      }
      MFMA_FENCE(acc);
#pragma unroll
      for (int r2 = 0; r2 < 4; ++r2) s_sim[(g * 16 + kg * 4 + r2) * 33 + n] = acc[r2];
    }
    __syncthreads();
    if (pw == 0) {  // secE: softmax + ca + (im | ep) on wave pw0 of each pair
      const int h = l & 31;
      float mx = -1e30f;
#pragma unroll
      for (int k = 0; k < 16; ++k) mx = fmaxf(mx, s_sim[(g * 16 + k) * 33 + h]);
      float sum = 0.f, o = 0.f;
#pragma unroll
      for (int k = 0; k < 16; ++k) {
        const float e = __expf(s_sim[(g * 16 + k) * 33 + h] - mx);
        sum += e;
        o = fmaf(e, uD[512 + k * 32 + h] + s_rpe[(g * 16 + k) * 33 + h], o);
      }
      const float ca = o / sum;
      if (s < 8) {
        float a = p.im_b1[h];
        for (int i2 = 0; i2 < 32; ++i2) a = fmaf(__shfl(ca, i2), p.im_w1[i2 * 32 + h], a);
        const float m1 = fmaxf(a, 0.f);
        a = p.im_b2[h];
        for (int i2 = 0; i2 < 32; ++i2) a = fmaf(__shfl(m1, i2), p.im_w2[i2 * 32 + h], a);
        const float m2 = fmaxf(a, 0.f);
        float p0 = m2 * p.im_w3[h * 3 + 0];
        float p1 = m2 * p.im_w3[h * 3 + 1];
        float p2 = m2 * p.im_w3[h * 3 + 2];
#pragma unroll
        for (int m = 1; m < 32; m <<= 1) {
          p0 += __shfl_xor(p0, m, 32);
          p1 += __shfl_xor(p1, m, 32);
          p2 += __shfl_xor(p2, m, 32);
        }
        p0 += p.im_b3[0]; p1 += p.im_b3[1]; p2 += p.im_b3[2];
        const float step = sqrtf(p0 * p0 + p1 * p1 + p2 * p2);
        const float cum = s_cum2[g];
        const float opc0 = s_qry2[g * 3 + 0] * cum;
        const float opc1 = s_qry2[g * 3 + 1] * cum;
        const float opc2 = s_qry2[g * 3 + 2] * cum;
        const float inv = 1.f / step;
        const float tg0 = p0 * inv, tg1 = p1 * inv, tg2 = p2 * inv;
        if (l == 0) {
          p.o_ms[bD * 8 + s] = step;
          p.o_ip[(bD * 8 + s) * 3 + 0] = opc0 + p0;
          s_op2[g * 3 + 0] = opc0 + s_qry2[g * 3 + 0] * step;
        } else if (l == 1) {
          p.o_ip[(bD * 8 + s) * 3 + 1] = opc1 + p1;
          s_op2[g * 3 + 1] = opc1 + s_qry2[g * 3 + 1] * step;
        } else if (l == 2) {
          p.o_ip[(bD * 8 + s) * 3 + 2] = opc2 + p2;
          s_op2[g * 3 + 2] = opc2 + s_qry2[g * 3 + 2] * step;
        } else if (l == 3) {
          s_cum2[g] = cum + step;
        }
        if (l < 16) {
          p.o_cs[bD * 128 + s * 16 + l] = tg0 * rv0 + tg1 * rv1 + tg2 * rv2;
        }
      } else {
        float a = p.ep_b1[h];
        for (int i2 = 0; i2 < 32; ++i2) a = fmaf(__shfl(ca, i2), p.ep_w1[i2 * 32 + h], a);
        a = fmaf(s_qry2[g * 3 + 0], p.ep_w1[1024 + h], a);
        a = fmaf(s_qry2[g * 3 + 1], p.ep_w1[1056 + h], a);
        a = fmaf(s_qry2[g * 3 + 2], p.ep_w1[1088 + h], a);
        const float e1 = fmaxf(a, 0.f);
        a = p.ep_b2[h];
        for (int i2 = 0; i2 < 32; ++i2) a = fmaf(__shfl(e1, i2), p.ep_w2[i2 * 32 + h], a);
        const float e2 = fmaxf(a, 0.f);
        float pp = e2 * p.ep_w3[h];
#pragma unroll
        for (int m = 1; m < 32; m <<= 1) pp += __shfl_xor(pp, m, 32);
        if (l == 0) {
          p.o_eps[bD] = pp + p.ep_b3[0];
          p.o_cum[bD] = s_cum2[g];
        }
      }
    }
    __syncthreads();
  }
}

extern "C" void kernel_launch(void* const* d_in, const int* in_sizes, int n_in,
                              void* d_out, int out_size, void* d_ws, size_t ws_size,
                              hipStream_t stream) {
  Params p;
  const float** f = (const float**)(void*)&p;
  for (int i = 0; i < 43; ++i) f[i] = (const float*)d_in[i];
  float* out = (float*)d_out;
  p.o_ld  = out;
  p.o_ms  = out + OFF_MS;
  p.o_cs  = out + OFF_CS;
  p.o_ip  = out + OFF_IP;
  p.o_cum = out + OFF_CUM;
  p.o_eps = out + OFF_EPS;
  puray_kernel<<<dim3(2048), dim3(256), 0, stream>>>(p);
}

// Round 12
// 1206.375 us; speedup vs baseline: 1.0802x; 1.0802x over previous
//
#include <hip/hip_runtime.h>

// Problem constants: B=4096, K=16, H=32, HM=128, STEPS=8
#define OFF_MS  524288
#define OFF_CS  557056
#define OFF_IP  1081344
#define OFF_CUM 1179648
#define OFF_EPS 1183744

#define HSTR 136   // padded bf16 row stride (272B -> 2-way banks, free)
#define BSTR 40    // padded bf16 row stride (80B)

struct Params {
  const float *knn, *query, *fw1, *fb1, *fw2, *fb2, *fw3, *fb3, *qkv_w,
    *ptp_w1, *ptp_b1, *ptp_w2, *ptp_b2, *pta_w1, *pta_b1, *pta_w2, *pta_b2,
    *caq_w, *caq_b, *cak_w, *cak_b, *cav_w, *cav_b,
    *cap_w1, *cap_b1, *cap_w2, *cap_b2, *caa_w1, *caa_b1, *caa_w2, *caa_b2,
    *im_w1, *im_b1, *im_w2, *im_b2, *im_w3, *im_b3,
    *ep_w1, *ep_b1, *ep_w2, *ep_b2, *ep_w3, *ep_b3;
  float *o_ld, *o_ms, *o_cs, *o_ip, *o_cum, *o_eps;
};
static_assert(sizeof(Params) == 49 * sizeof(void*), "Params layout");

typedef float f32x4 __attribute__((ext_vector_type(4)));
typedef unsigned short u16x8 __attribute__((ext_vector_type(8)));

__device__ __forceinline__ unsigned short f2b(float x) {  // fp32->bf16 RNE
  unsigned u = __float_as_uint(x);
  u += 0x7fffu + ((u >> 16) & 1u);
  return (unsigned short)(u >> 16);
}
__device__ __forceinline__ unsigned pack2(float lo, float hi) {
  return (unsigned)f2b(lo) | ((unsigned)f2b(hi) << 16);
}

#define MFMA(acc, a, bb) \
  asm volatile("s_nop 2\n\tv_mfma_f32_16x16x32_bf16 %0, %1, %2, %0" \
               : "+v"(acc) : "v"(a), "v"(bb))
#define MFMA_FENCE(acc) asm volatile("s_nop 7\n\ts_nop 7" : "+v"(acc))

// DUAL-BATCH take 2. Round-11 spilled because phase-D secA used a 32-hv/lane
// shape (register blowup at the 128-VGPR cap). This version keeps EVERY
// section in a round-9/10-proven shape (max 16 live accs/thread):
//  - secA: all 256 threads, r=t>>3 over 32 rows (both batches), 16 hv each
//    == phase-C sec1a shape (compiled 104 VGPR).
//  - qq chain: waves 0,1 (batch=w), identical code to round-10's wave0 chain.
//  - secB/C/D: pair-tiled (waves {0,1}=batch0, {2,3}=batch1), 4-8 accs.
//  - secE: waves 0,1 (batch=w) -- rv regs live in the same waves.
// (256,2): the only no-spill config on this toolchain.
__launch_bounds__(256, 2)
__global__ void puray_kernel(Params p) {
  const int b0 = blockIdx.x * 2;
  const int t = threadIdx.x;
  const int w = t >> 6, l = t & 63;
  const int ln16 = l & 15, kg = l >> 4, k0 = kg * 8;

  __shared__ __align__(16) unsigned short s_wTA[32 * HSTR];  // ptp_w2T -> cap_w2T [n][k]
  __shared__ __align__(16) unsigned short s_wTB[128 * BSTR]; // pta_w1T -> caa_w1T [n][k]
  __shared__ __align__(16) unsigned short s_wTC[32 * HSTR];  // pta_w2T -> caa_w2T [n][k]
  __shared__ __align__(16) unsigned short s_hidb[32 * HSTR]; // C: 32 rows; D: [g][16]
  __shared__ __align__(16) unsigned short s_simb[32 * BSTR];
  __shared__ float s_rpe[32 * 33];
  __shared__ float s_sim[32 * 33];
  __shared__ float s_v[512], s_feats[512];
  __shared__ float s_uD[2048];        // per batch: C-time q|k, D-time kk|vvb
  __shared__ float s_coords2[96], s_relv2[96], s_reld2[32];
  __shared__ float s_qry2[6], s_op2[6], s_cum2[2], s_qq2[64];

  // ---- stage ptp/pta weights (shared by both batches) + per-batch scalars ----
#pragma unroll 4
  for (int m = 0; m < 16; ++m) {
    const int idx = t + 256 * m;
    { const int n = idx >> 7, k = idx & 127;
      s_wTA[n * HSTR + k] = f2b(p.ptp_w2[k * 32 + n]);
      s_wTC[n * HSTR + k] = f2b(p.pta_w2[k * 32 + n]); }
    { const int n = idx >> 5, k = idx & 31;
      s_wTB[n * BSTR + k] = f2b(p.pta_w1[k * 128 + n]); }
  }
  if (t < 96) s_coords2[t] = p.knn[b0 * 48 + t];
  else if (t < 102) s_qry2[t - 96] = p.query[b0 * 3 + (t - 96)];
  else if (t < 104) s_cum2[t - 102] = 0.f;
  else if (t < 110) s_op2[t - 104] = 0.f;
  __syncthreads();

  // ================= Phases A/B/C per batch (sequential) =================
  for (int gg = 0; gg < 2; ++gg) {
    const float* cg = s_coords2 + gg * 48;
    float* uq = s_uD + gg * 1024;   // q | k during this batch's C

    // ---- Phase A ----
#pragma unroll
    for (int m = 0; m < 2; ++m) {
      const int l2 = t + 256 * m, pp = l2 >> 5, jj = l2 & 31;
      float a = p.fb1[jj];
#pragma unroll
      for (int c = 0; c < 3; ++c) a = fmaf(cg[pp * 3 + c], p.fw1[c * 32 + jj], a);
      s_rpe[l2] = fmaxf(a, 0.f);
    }
    __syncthreads();
#pragma unroll
    for (int m = 0; m < 2; ++m) {
      const int l2 = t + 256 * m, pp = l2 >> 5, jj = l2 & 31;
      float a = p.fb2[jj];
      for (int i = 0; i < 32; ++i) a = fmaf(s_rpe[pp * 32 + i], p.fw2[i * 32 + jj], a);
      s_sim[l2] = fmaxf(a, 0.f);
    }
    __syncthreads();
#pragma unroll
    for (int m = 0; m < 2; ++m) {
      const int l2 = t + 256 * m, pp = l2 >> 5, jj = l2 & 31;
      float a = p.fb3[jj];
      for (int i = 0; i < 32; ++i) a = fmaf(s_sim[pp * 32 + i], p.fw3[i * 32 + jj], a);
      s_feats[l2] = a;
    }
    __syncthreads();

    // ---- Phase B: qkv ----
#pragma unroll
    for (int m = 0; m < 6; ++m) {
      const int l2 = t + 256 * m, pp = l2 / 96, o = l2 % 96;
      float a = 0.f;
      for (int i = 0; i < 32; ++i) a = fmaf(s_feats[pp * 32 + i], p.qkv_w[i * 96 + o], a);
      if (o < 32) uq[pp * 32 + o] = a;
      else if (o < 64) uq[512 + pp * 32 + o - 32] = a;
      else s_v[pp * 32 + o - 64] = a;
    }
    __syncthreads();

    // ---- Phase C ----
    for (int ig = 0; ig < 16; ig += 2) {
      {  // sec1a: hv[32][128]
        const int r = t >> 3;
        const int i = ig + (r >> 4), j = r & 15;
        const float r0 = cg[i * 3 + 0] - cg[j * 3 + 0];
        const float r1 = cg[i * 3 + 1] - cg[j * 3 + 1];
        const float r2 = cg[i * 3 + 2] - cg[j * 3 + 2];
        const int d0 = (t & 7) * 16;
#pragma unroll
        for (int x = 0; x < 16; x += 2) {
          const int d = d0 + x;
          const float h0v = fmaxf(fmaf(r0, p.ptp_w1[d],
                             fmaf(r1, p.ptp_w1[128 + d],
                             fmaf(r2, p.ptp_w1[256 + d], p.ptp_b1[d]))), 0.f);
          const float h1v = fmaxf(fmaf(r0, p.ptp_w1[d + 1],
                             fmaf(r1, p.ptp_w1[128 + d + 1],
                             fmaf(r2, p.ptp_w1[256 + d + 1], p.ptp_b1[d + 1]))), 0.f);
          ((unsigned*)s_hidb)[(r * HSTR + d) >> 1] = pack2(h0v, h1v);
        }
      }
      __syncthreads();
      {  // G1: rpe = hv @ ptp_w2 + b2; simin -> s_simb
        const int mb = w >> 1, nb = w & 1, n = nb * 16 + ln16;
        const float bias = p.ptp_b2[n];
        f32x4 acc = {bias, bias, bias, bias};
#pragma unroll
        for (int kk = 0; kk < 4; ++kk) {
          const u16x8 a = *(const u16x8*)&s_hidb[(mb * 16 + ln16) * HSTR + kk * 32 + k0];
          const u16x8 bb = *(const u16x8*)&s_wTA[n * HSTR + kk * 32 + k0];
          MFMA(acc, a, bb);
        }
        MFMA_FENCE(acc);
#pragma unroll
        for (int r2 = 0; r2 < 4; ++r2) {
          const int row = mb * 16 + kg * 4 + r2;
          const float val = acc[r2];
          s_rpe[row * 33 + n] = val;
          const int i = ig + (row >> 4), j = row & 15;
          s_simb[row * BSTR + n] = f2b(uq[i * 32 + n] - uq[512 + j * 32 + n] + val);
        }
      }
      __syncthreads();
      {  // G2: hid = relu(simin @ pta_w1 + b1)
        const int mb = w & 1;
        const u16x8 a = *(const u16x8*)&s_simb[(mb * 16 + ln16) * BSTR + k0];
#pragma unroll
        for (int j2 = 0; j2 < 4; ++j2) {
          const int n = ((w >> 1) * 4 + j2) * 16 + ln16;
          const u16x8 bb = *(const u16x8*)&s_wTB[n * BSTR + k0];
          const float bias = p.pta_b1[n];
          f32x4 acc = {bias, bias, bias, bias};
          MFMA(acc, a, bb);
          MFMA_FENCE(acc);
#pragma unroll
          for (int r2 = 0; r2 < 4; ++r2)
            s_hidb[(mb * 16 + kg * 4 + r2) * HSTR + n] = f2b(fmaxf(acc[r2], 0.f));
        }
      }
      __syncthreads();
      {  // G3: sim = hid @ pta_w2 + b2 -> s_sim (fp32)
        const int mb = w >> 1, nb = w & 1, n = nb * 16 + ln16;
        const float bias = p.pta_b2[n];
        f32x4 acc = {bias, bias, bias, bias};
#pragma unroll
        for (int kk = 0; kk < 4; ++kk) {
          const u16x8 a = *(const u16x8*)&s_hidb[(mb * 16 + ln16) * HSTR + kk * 32 + k0];
          const u16x8 bb = *(const u16x8*)&s_wTC[n * HSTR + kk * 32 + k0];
          MFMA(acc, a, bb);
        }
        MFMA_FENCE(acc);
#pragma unroll
        for (int r2 = 0; r2 < 4; ++r2) s_sim[(mb * 16 + kg * 4 + r2) * 33 + n] = acc[r2];
      }
      __syncthreads();
      if (t < 64) {  // sec4: softmax + weighted sum
        const int g2 = t >> 5, h = t & 31;
        float mx = -1e30f;
#pragma unroll
        for (int j2 = 0; j2 < 16; ++j2) mx = fmaxf(mx, s_sim[(g2 * 16 + j2) * 33 + h]);
        float sum = 0.f, o = 0.f;
#pragma unroll
        for (int j2 = 0; j2 < 16; ++j2) {
          const float e = __expf(s_sim[(g2 * 16 + j2) * 33 + h] - mx);
          sum += e;
          o = fmaf(e, s_v[j2 * 32 + h] + s_rpe[(g2 * 16 + j2) * 33 + h], o);
        }
        s_feats[(ig + g2) * 32 + h] = o / sum;
      }
      __syncthreads();
    }

    // ---- kk/vvb for this batch (overwrites q|k region) ----
#pragma unroll
    for (int m = 0; m < 2; ++m) {
      const int l2 = t + 256 * m, k = l2 >> 5, h = l2 & 31;
      float akk = p.cak_b[h], avv = p.cav_b[h];
      for (int i = 0; i < 32; ++i) {
        const float f = s_feats[k * 32 + i];
        akk = fmaf(f, p.cak_w[i * 32 + h], akk);
        avv = fmaf(f, p.cav_w[i * 32 + h], avv);
      }
      uq[k * 32 + h] = akk;
      uq[512 + k * 32 + h] = avv;
    }
    __syncthreads();
  }

  // ---- restage weights for cross-attention ----
#pragma unroll 4
  for (int m = 0; m < 16; ++m) {
    const int idx = t + 256 * m;
    { const int n = idx >> 7, k = idx & 127;
      s_wTA[n * HSTR + k] = f2b(p.cap_w2[k * 32 + n]);
      s_wTC[n * HSTR + k] = f2b(p.caa_w2[k * 32 + n]); }
    { const int n = idx >> 5, k = idx & 31;
      s_wTB[n * BSTR + k] = f2b(p.caa_w1[k * 128 + n]); }
  }
  __syncthreads();

  // ================= Phase D: both batches concurrently =================
  for (int s = 0; s <= 8; ++s) {
    float rv0 = 0.f, rv1 = 0.f, rv2 = 0.f;
    {  // secA: all 256 threads, 32 rows (both batches), 16 hv each
      const int r = t >> 3;                 // 0..31
      const int gA = r >> 4, k = r & 15;
      const float* cA = s_coords2 + gA * 48;
      float c0, c1, c2;
      if (s < 8) {
        c0 = cA[k * 3 + 0] - s_op2[gA * 3 + 0];
        c1 = cA[k * 3 + 1] - s_op2[gA * 3 + 1];
        c2 = cA[k * 3 + 2] - s_op2[gA * 3 + 2];
      } else {  // stale rel from step 7 (reference semantics)
        const float rd = s_reld2[gA * 16 + k];
        c0 = s_relv2[gA * 48 + k * 3 + 0] * rd;
        c1 = s_relv2[gA * 48 + k * 3 + 1] * rd;
        c2 = s_relv2[gA * 48 + k * 3 + 2] * rd;
      }
      const int d0 = (t & 7) * 16;
#pragma unroll
      for (int x = 0; x < 16; x += 2) {
        const int d = d0 + x;
        const float h0v = fmaxf(fmaf(c0, p.cap_w1[d],
                           fmaf(c1, p.cap_w1[128 + d],
                           fmaf(c2, p.cap_w1[256 + d], p.cap_b1[d]))), 0.f);
        const float h1v = fmaxf(fmaf(c0, p.cap_w1[d + 1],
                           fmaf(c1, p.cap_w1[128 + d + 1],
                           fmaf(c2, p.cap_w1[256 + d + 1], p.cap_b1[d + 1]))), 0.f);
        ((unsigned*)s_hidb)[(r * HSTR + d) >> 1] = pack2(h0v, h1v);
      }
    }
    if (t < 128) {  // waves 0,1: rel/o_ld + qq chain, batch = w
      const float* cq = s_coords2 + w * 48;
      const int h = l & 31;
      if (s < 8 && l < 16) {
        const float r0 = cq[l * 3 + 0] - s_op2[w * 3 + 0];
        const float r1 = cq[l * 3 + 1] - s_op2[w * 3 + 1];
        const float r2 = cq[l * 3 + 2] - s_op2[w * 3 + 2];
        const float rd = sqrtf(r0 * r0 + r1 * r1 + r2 * r2);
        const float inv = 1.f / rd;
        rv0 = r0 * inv; rv1 = r1 * inv; rv2 = r2 * inv;
        s_reld2[w * 16 + l] = rd;
        s_relv2[w * 48 + l * 3 + 0] = rv0;
        s_relv2[w * 48 + l * 3 + 1] = rv1;
        s_relv2[w * 48 + l * 3 + 2] = rv2;
        p.o_ld[(b0 + w) * 128 + s * 16 + l] = rd;
      }
      float opc0, opc1, opc2;
      if (s < 8) {
        const float cum = s_cum2[w];
        opc0 = s_qry2[w * 3 + 0] * cum; opc1 = s_qry2[w * 3 + 1] * cum; opc2 = s_qry2[w * 3 + 2] * cum;
      } else {
        opc0 = s_op2[w * 3 + 0]; opc1 = s_op2[w * 3 + 1]; opc2 = s_op2[w * 3 + 2];
      }
      float v1 = fmaxf(fmaf(opc0, p.fw1[h],
                    fmaf(opc1, p.fw1[32 + h],
                    fmaf(opc2, p.fw1[64 + h], p.fb1[h]))), 0.f);
      float a = p.fb2[h];
      for (int i2 = 0; i2 < 32; ++i2) a = fmaf(__shfl(v1, i2, 32), p.fw2[i2 * 32 + h], a);
      const float v2 = fmaxf(a, 0.f);
      a = p.fb3[h];
      for (int i2 = 0; i2 < 32; ++i2) a = fmaf(__shfl(v2, i2, 32), p.fw3[i2 * 32 + h], a);
      const float opf = a;
      a = p.caq_b[h];
      for (int i2 = 0; i2 < 32; ++i2) a = fmaf(__shfl(opf, i2, 32), p.caq_w[i2 * 32 + h], a);
      if (l < 32) s_qq2[w * 32 + h] = a;
    }
    __syncthreads();
    {  // secB: pe = hv @ cap_w2 + b2; fused ain -> s_simb (pair-tiled)
      const int g = w >> 1, pw = w & 1;
      const float* uB = s_uD + g * 1024;
      const int n = pw * 16 + ln16;
      const float bias = p.cap_b2[n];
      f32x4 acc = {bias, bias, bias, bias};
#pragma unroll
      for (int kk = 0; kk < 4; ++kk) {
        const u16x8 a = *(const u16x8*)&s_hidb[(g * 16 + ln16) * HSTR + kk * 32 + k0];
        const u16x8 bb = *(const u16x8*)&s_wTA[n * HSTR + kk * 32 + k0];
        MFMA(acc, a, bb);
      }
      MFMA_FENCE(acc);
#pragma unroll
      for (int r2 = 0; r2 < 4; ++r2) {
        const int row = kg * 4 + r2;
        const float pe = acc[r2];
        s_rpe[(g * 16 + row) * 33 + n] = pe;
        s_simb[(g * 16 + row) * BSTR + n] = f2b(s_qq2[g * 32 + n] - uB[row * 32 + n] + pe);
      }
    }
    __syncthreads();
    {  // secC: hid = relu(ain @ caa_w1 + b1) (pair-tiled, 4 n-tiles/wave)
      const int g = w >> 1, pw = w & 1;
      const u16x8 a = *(const u16x8*)&s_simb[(g * 16 + ln16) * BSTR + k0];
#pragma unroll
      for (int j2 = 0; j2 < 4; ++j2) {
        const int n = (pw * 4 + j2) * 16 + ln16;
        const u16x8 bb = *(const u16x8*)&s_wTB[n * BSTR + k0];
        const float bias = p.caa_b1[n];
        f32x4 acc = {bias, bias, bias, bias};
        MFMA(acc, a, bb);
        MFMA_FENCE(acc);
#pragma unroll
        for (int r2 = 0; r2 < 4; ++r2)
          s_hidb[(g * 16 + kg * 4 + r2) * HSTR + n] = f2b(fmaxf(acc[r2], 0.f));
      }
    }
    __syncthreads();
    {  // secD: sim = hid @ caa_w2 + b2 -> s_sim (fp32, pair-tiled)
      const int g = w >> 1, pw = w & 1;
      const int n = pw * 16 + ln16;
      const float bias = p.caa_b2[n];
      f32x4 acc = {bias, bias, bias, bias};
#pragma unroll
      for (int kk = 0; kk < 4; ++kk) {
        const u16x8 a = *(const u16x8*)&s_hidb[(g * 16 + ln16) * HSTR + kk * 32 + k0];
        const u16x8 bb = *(const u16x8*)&s_wTC[n * HSTR + kk * 32 + k0];
        MFMA(acc, a, bb);
      }
      MFMA_FENCE(acc);
#pragma unroll
      for (int r2 = 0; r2 < 4; ++r2) s_sim[(g * 16 + kg * 4 + r2) * 33 + n] = acc[r2];
    }
    __syncthreads();
    if (t < 128) {  // secE: softmax + ca + (im | ep), waves 0,1, batch = w
      const float* uE = s_uD + w * 1024;
      const int bD = b0 + w;
      const int h = l & 31;
      float mx = -1e30f;
#pragma unroll
      for (int k = 0; k < 16; ++k) mx = fmaxf(mx, s_sim[(w * 16 + k) * 33 + h]);
      float sum = 0.f, o = 0.f;
#pragma unroll
      for (int k = 0; k < 16; ++k) {
        const float e = __expf(s_sim[(w * 16 + k) * 33 + h] - mx);
        sum += e;
        o = fmaf(e, uE[512 + k * 32 + h] + s_rpe[(w * 16 + k) * 33 + h], o);
      }
      const float ca = o / sum;
      if (s < 8) {
        float a = p.im_b1[h];
        for (int i2 = 0; i2 < 32; ++i2) a = fmaf(__shfl(ca, i2, 32), p.im_w1[i2 * 32 + h], a);
        const float m1 = fmaxf(a, 0.f);
        a = p.im_b2[h];
        for (int i2 = 0; i2 < 32; ++i2) a = fmaf(__shfl(m1, i2, 32), p.im_w2[i2 * 32 + h], a);
        const float m2 = fmaxf(a, 0.f);
        float p0 = m2 * p.im_w3[h * 3 + 0];
        float p1 = m2 * p.im_w3[h * 3 + 1];
        float p2 = m2 * p.im_w3[h * 3 + 2];
#pragma unroll
        for (int m = 1; m < 32; m <<= 1) {
          p0 += __shfl_xor(p0, m, 32);
          p1 += __shfl_xor(p1, m, 32);
          p2 += __shfl_xor(p2, m, 32);
        }
        p0 += p.im_b3[0]; p1 += p.im_b3[1]; p2 += p.im_b3[2];
        const float step = sqrtf(p0 * p0 + p1 * p1 + p2 * p2);
        const float cum = s_cum2[w];
        const float opc0 = s_qry2[w * 3 + 0] * cum;
        const float opc1 = s_qry2[w * 3 + 1] * cum;
        const float opc2 = s_qry2[w * 3 + 2] * cum;
        const float inv = 1.f / step;
        const float tg0 = p0 * inv, tg1 = p1 * inv, tg2 = p2 * inv;
        if (l == 0) {
          p.o_ms[bD * 8 + s] = step;
          p.o_ip[(bD * 8 + s) * 3 + 0] = opc0 + p0;
          s_op2[w * 3 + 0] = opc0 + s_qry2[w * 3 + 0] * step;
        } else if (l == 1) {
          p.o_ip[(bD * 8 + s) * 3 + 1] = opc1 + p1;
          s_op2[w * 3 + 1] = opc1 + s_qry2[w * 3 + 1] * step;
        } else if (l == 2) {
          p.o_ip[(bD * 8 + s) * 3 + 2] = opc2 + p2;
          s_op2[w * 3 + 2] = opc2 + s_qry2[w * 3 + 2] * step;
        } else if (l == 3) {
          s_cum2[w] = cum + step;
        }
        if (l < 16) {
          p.o_cs[bD * 128 + s * 16 + l] = tg0 * rv0 + tg1 * rv1 + tg2 * rv2;
        }
      } else {
        float a = p.ep_b1[h];
        for (int i2 = 0; i2 < 32; ++i2) a = fmaf(__shfl(ca, i2, 32), p.ep_w1[i2 * 32 + h], a);
        a = fmaf(s_qry2[w * 3 + 0], p.ep_w1[1024 + h], a);
        a = fmaf(s_qry2[w * 3 + 1], p.ep_w1[1056 + h], a);
        a = fmaf(s_qry2[w * 3 + 2], p.ep_w1[1088 + h], a);
        const float e1 = fmaxf(a, 0.f);
        a = p.ep_b2[h];
        for (int i2 = 0; i2 < 32; ++i2) a = fmaf(__shfl(e1, i2, 32), p.ep_w2[i2 * 32 + h], a);
        const float e2 = fmaxf(a, 0.f);
        float pp = e2 * p.ep_w3[h];
#pragma unroll
        for (int m = 1; m < 32; m <<= 1) pp += __shfl_xor(pp, m, 32);
        if (l == 0) {
          p.o_eps[bD] = pp + p.ep_b3[0];
          p.o_cum[bD] = s_cum2[w];
        }
      }
    }
    __syncthreads();
  }
}

extern "C" void kernel_launch(void* const* d_in, const int* in_sizes, int n_in,
                              void* d_out, int out_size, void* d_ws, size_t ws_size,
                              hipStream_t stream) {
  Params p;
  const float** f = (const float**)(void*)&p;
  for (int i = 0; i < 43; ++i) f[i] = (const float*)d_in[i];
  float* out = (float*)d_out;
  p.o_ld  = out;
  p.o_ms  = out + OFF_MS;
  p.o_cs  = out + OFF_CS;
  p.o_ip  = out + OFF_IP;
  p.o_cum = out + OFF_CUM;
  p.o_eps = out + OFF_EPS;
  puray_kernel<<<dim3(2048), dim3(256), 0, stream>>>(p);
}

// Round 13
// 863.284 us; speedup vs baseline: 1.5095x; 1.3974x over previous
//
#include <hip/hip_runtime.h>

// Problem constants: B=4096, K=16, H=32, HM=128, STEPS=8
#define OFF_MS  524288
#define OFF_CS  557056
#define OFF_IP  1081344
#define OFF_CUM 1179648
#define OFF_EPS 1183744

#define HSTR 136   // padded bf16 row stride (272B -> 2-way banks, free)
#define BSTR 40    // padded bf16 row stride (80B)

struct Params {
  const float *knn, *query, *fw1, *fb1, *fw2, *fb2, *fw3, *fb3, *qkv_w,
    *ptp_w1, *ptp_b1, *ptp_w2, *ptp_b2, *pta_w1, *pta_b1, *pta_w2, *pta_b2,
    *caq_w, *caq_b, *cak_w, *cak_b, *cav_w, *cav_b,
    *cap_w1, *cap_b1, *cap_w2, *cap_b2, *caa_w1, *caa_b1, *caa_w2, *caa_b2,
    *im_w1, *im_b1, *im_w2, *im_b2, *im_w3, *im_b3,
    *ep_w1, *ep_b1, *ep_w2, *ep_b2, *ep_w3, *ep_b3;
  float *o_ld, *o_ms, *o_cs, *o_ip, *o_cum, *o_eps;
};
static_assert(sizeof(Params) == 49 * sizeof(void*), "Params layout");

typedef float f32x4 __attribute__((ext_vector_type(4)));
typedef unsigned short u16x8 __attribute__((ext_vector_type(8)));

__device__ __forceinline__ unsigned short f2b(float x) {  // fp32->bf16 RNE
  unsigned u = __float_as_uint(x);
  u += 0x7fffu + ((u >> 16) & 1u);
  return (unsigned short)(u >> 16);
}
__device__ __forceinline__ unsigned pack2(float lo, float hi) {
  return (unsigned)f2b(lo) | ((unsigned)f2b(hi) << 16);
}

#define MFMA(acc, a, bb) \
  asm volatile("s_nop 2\n\tv_mfma_f32_16x16x32_bf16 %0, %1, %2, %0" \
               : "+v"(acc) : "v"(a), "v"(bb))
#define MFMA_FENCE(acc) asm volatile("s_nop 7\n\ts_nop 7" : "+v"(acc))

// Round-10 base (783us, 104 VGPR, no spill). Phase C restructured:
//  - 4 i-rows/iteration (M=64): 4 iterations x 4 barriers = 16 barriers
//    (was 8 x 6 = 48). sec1a keeps the PROVEN 16-hv/thread shape via two
//    sequential 32-row passes (round-11's 32-hv shape spilled).
//  - softmax fused into G3 epilogue: G1's rpe tile stays in named f32x4
//    regs (rpe0/rpe1) through G2/G3; 16-row reduce via __shfl_xor(16/32).
//    s_rpe/s_sim are phase-D-only now (16x33 each).
// Phase D byte-identical to round 10. Single batch per block, grid 4096.
// (256,2): the only no-spill config on this toolchain.
__launch_bounds__(256, 2)
__global__ void puray_kernel(Params p) {
  const int b = blockIdx.x;
  const int t = threadIdx.x;
  const int w = t >> 6, l = t & 63;
  const int ln16 = l & 15, kg = l >> 4, k0 = kg * 8;

  __shared__ __align__(16) unsigned short s_wTA[32 * HSTR];  // ptp_w2T -> cap_w2T [n][k]
  __shared__ __align__(16) unsigned short s_wTB[128 * BSTR]; // pta_w1T -> caa_w1T [n][k]
  __shared__ __align__(16) unsigned short s_wTC[32 * HSTR];  // pta_w2T -> caa_w2T [n][k]
  __shared__ __align__(16) unsigned short s_hidb[64 * HSTR]; // bf16 act, 64 rows
  __shared__ __align__(16) unsigned short s_simb[64 * BSTR];
  __shared__ float s_rpe[16 * 33 + 16];   // phase D pe (also phase-A h1 scratch, needs 512)
  __shared__ float s_sim[16 * 33 + 16];   // phase D sim (also phase-A h2 scratch)
  __shared__ float s_v[512], s_feats[512];
  __shared__ float s_u[1024];             // C: q|k ; D: kk|vvb
  __shared__ float s_coords[48], s_relv[48], s_reld[16];
  __shared__ float s_qry[3], s_op[3], s_qq[32];
  __shared__ float s_cum;

  // ---- stage: transpose+convert phase-C weights to bf16 [N][K] (padded) ----
#pragma unroll 4
  for (int m = 0; m < 16; ++m) {
    const int idx = t + 256 * m;
    { const int n = idx >> 7, k = idx & 127;
      s_wTA[n * HSTR + k] = f2b(p.ptp_w2[k * 32 + n]);
      s_wTC[n * HSTR + k] = f2b(p.pta_w2[k * 32 + n]); }
    { const int n = idx >> 5, k = idx & 31;
      s_wTB[n * BSTR + k] = f2b(p.pta_w1[k * 128 + n]); }
  }
  if (t < 48) s_coords[t] = p.knn[b * 48 + t];
  else if (t < 51) s_qry[t - 48] = p.query[b * 3 + (t - 48)];
  else if (t == 51) s_cum = 0.f;
  else if (t < 55) s_op[t - 52] = 0.f;
  __syncthreads();

  // ---- Phase A: feats (scratch: s_rpe=h1, s_sim=h2) ----
#pragma unroll
  for (int m = 0; m < 2; ++m) {
    const int l2 = t + 256 * m, pp = l2 >> 5, jj = l2 & 31;
    float a = p.fb1[jj];
#pragma unroll
    for (int c = 0; c < 3; ++c) a = fmaf(s_coords[pp * 3 + c], p.fw1[c * 32 + jj], a);
    s_rpe[l2] = fmaxf(a, 0.f);
  }
  __syncthreads();
#pragma unroll
  for (int m = 0; m < 2; ++m) {
    const int l2 = t + 256 * m, pp = l2 >> 5, jj = l2 & 31;
    float a = p.fb2[jj];
    for (int i = 0; i < 32; ++i) a = fmaf(s_rpe[pp * 32 + i], p.fw2[i * 32 + jj], a);
    s_sim[l2] = fmaxf(a, 0.f);
  }
  __syncthreads();
#pragma unroll
  for (int m = 0; m < 2; ++m) {
    const int l2 = t + 256 * m, pp = l2 >> 5, jj = l2 & 31;
    float a = p.fb3[jj];
    for (int i = 0; i < 32; ++i) a = fmaf(s_sim[pp * 32 + i], p.fw3[i * 32 + jj], a);
    s_feats[l2] = a;
  }
  __syncthreads();

  // ---- Phase B: qkv ----
#pragma unroll
  for (int m = 0; m < 6; ++m) {
    const int l2 = t + 256 * m, pp = l2 / 96, o = l2 % 96;
    float a = 0.f;
    for (int i = 0; i < 32; ++i) a = fmaf(s_feats[pp * 32 + i], p.qkv_w[i * 96 + o], a);
    if (o < 32) s_u[pp * 32 + o] = a;
    else if (o < 64) s_u[512 + pp * 32 + o - 32] = a;
    else s_v[pp * 32 + o - 64] = a;
  }
  __syncthreads();

  // ---- Phase C: 4 i-rows per iteration (M=64), 4 barriers/iter ----
  for (int ig = 0; ig < 16; ig += 4) {
    // sec1a: hv[64][128], two sequential 32-row passes (proven 16-hv shape)
    for (int half = 0; half < 2; ++half) {
      const int r = half * 32 + (t >> 3);
      const int i = ig + (r >> 4), j = r & 15;
      const float r0 = s_coords[i * 3 + 0] - s_coords[j * 3 + 0];
      const float r1 = s_coords[i * 3 + 1] - s_coords[j * 3 + 1];
      const float r2 = s_coords[i * 3 + 2] - s_coords[j * 3 + 2];
      const int d0 = (t & 7) * 16;
#pragma unroll
      for (int x = 0; x < 16; x += 2) {
        const int d = d0 + x;
        const float h0v = fmaxf(fmaf(r0, p.ptp_w1[d],
                           fmaf(r1, p.ptp_w1[128 + d],
                           fmaf(r2, p.ptp_w1[256 + d], p.ptp_b1[d]))), 0.f);
        const float h1v = fmaxf(fmaf(r0, p.ptp_w1[d + 1],
                           fmaf(r1, p.ptp_w1[128 + d + 1],
                           fmaf(r2, p.ptp_w1[256 + d + 1], p.ptp_b1[d + 1]))), 0.f);
        ((unsigned*)s_hidb)[(r * HSTR + d) >> 1] = pack2(h0v, h1v);
      }
    }
    __syncthreads();
    // G1: rpe tiles (kept in regs) + simb. Wave w owns rows w*16..w*16+15.
    f32x4 rpe0, rpe1;
    {
      const int i = ig + w;
      const int arow = (w * 16 + ln16) * HSTR;
      {  // nb = 0
        const int n = ln16;
        const float bias = p.ptp_b2[n];
        f32x4 acc = {bias, bias, bias, bias};
#pragma unroll
        for (int kk = 0; kk < 4; ++kk) {
          const u16x8 a = *(const u16x8*)&s_hidb[arow + kk * 32 + k0];
          const u16x8 bb = *(const u16x8*)&s_wTA[n * HSTR + kk * 32 + k0];
          MFMA(acc, a, bb);
        }
        MFMA_FENCE(acc);
        rpe0 = acc;
#pragma unroll
        for (int r2 = 0; r2 < 4; ++r2) {
          const int j = kg * 4 + r2;
          s_simb[(w * 16 + j) * BSTR + n] =
            f2b(s_u[i * 32 + n] - s_u[512 + j * 32 + n] + acc[r2]);
        }
      }
      {  // nb = 1
        const int n = 16 + ln16;
        const float bias = p.ptp_b2[n];
        f32x4 acc = {bias, bias, bias, bias};
#pragma unroll
        for (int kk = 0; kk < 4; ++kk) {
          const u16x8 a = *(const u16x8*)&s_hidb[arow + kk * 32 + k0];
          const u16x8 bb = *(const u16x8*)&s_wTA[n * HSTR + kk * 32 + k0];
          MFMA(acc, a, bb);
        }
        MFMA_FENCE(acc);
        rpe1 = acc;
#pragma unroll
        for (int r2 = 0; r2 < 4; ++r2) {
          const int j = kg * 4 + r2;
          s_simb[(w * 16 + j) * BSTR + n] =
            f2b(s_u[i * 32 + n] - s_u[512 + j * 32 + n] + acc[r2]);
        }
      }
    }
    __syncthreads();
    {  // G2: hid[64][128] = relu(simin @ pta_w1 + b1); wave w = rows w*16..
      const u16x8 a = *(const u16x8*)&s_simb[(w * 16 + ln16) * BSTR + k0];
#pragma unroll
      for (int j2 = 0; j2 < 8; ++j2) {
        const int n = j2 * 16 + ln16;
        const u16x8 bb = *(const u16x8*)&s_wTB[n * BSTR + k0];
        const float bias = p.pta_b1[n];
        f32x4 acc = {bias, bias, bias, bias};
        MFMA(acc, a, bb);
        MFMA_FENCE(acc);
#pragma unroll
        for (int r2 = 0; r2 < 4; ++r2)
          s_hidb[(w * 16 + kg * 4 + r2) * HSTR + n] = f2b(fmaxf(acc[r2], 0.f));
      }
    }
    __syncthreads();
    {  // G3 + fused softmax: sim tile -> softmax over 16 j -> feats[i]
      const int i = ig + w;
      const int arow = (w * 16 + ln16) * HSTR;
#pragma unroll
      for (int nb = 0; nb < 2; ++nb) {
        const int n = nb * 16 + ln16;
        const float bias = p.pta_b2[n];
        f32x4 acc = {bias, bias, bias, bias};
#pragma unroll
        for (int kk = 0; kk < 4; ++kk) {
          const u16x8 a = *(const u16x8*)&s_hidb[arow + kk * 32 + k0];
          const u16x8 bb = *(const u16x8*)&s_wTC[n * HSTR + kk * 32 + k0];
          MFMA(acc, a, bb);
        }
        MFMA_FENCE(acc);
        const f32x4 rp = nb ? rpe1 : rpe0;
        float mx = fmaxf(fmaxf(acc[0], acc[1]), fmaxf(acc[2], acc[3]));
        mx = fmaxf(mx, __shfl_xor(mx, 16));
        mx = fmaxf(mx, __shfl_xor(mx, 32));
        float sum = 0.f, o = 0.f;
#pragma unroll
        for (int r2 = 0; r2 < 4; ++r2) {
          const int j = kg * 4 + r2;
          const float e = __expf(acc[r2] - mx);
          sum += e;
          o = fmaf(e, s_v[j * 32 + n] + rp[r2], o);
        }
        sum += __shfl_xor(sum, 16); o += __shfl_xor(o, 16);
        sum += __shfl_xor(sum, 32); o += __shfl_xor(o, 32);
        if (kg == 0) s_feats[i * 32 + n] = o / sum;
      }
    }
    __syncthreads();
  }

  // ---- restage weights (cap/caa) + hoisted kk/vv ----
#pragma unroll 4
  for (int m = 0; m < 16; ++m) {
    const int idx = t + 256 * m;
    { const int n = idx >> 7, k = idx & 127;
      s_wTA[n * HSTR + k] = f2b(p.cap_w2[k * 32 + n]);
      s_wTC[n * HSTR + k] = f2b(p.caa_w2[k * 32 + n]); }
    { const int n = idx >> 5, k = idx & 31;
      s_wTB[n * BSTR + k] = f2b(p.caa_w1[k * 128 + n]); }
  }
#pragma unroll
  for (int m = 0; m < 2; ++m) {
    const int l2 = t + 256 * m, k = l2 >> 5, h = l2 & 31;
    float akk = p.cak_b[h], avv = p.cav_b[h];
    for (int i = 0; i < 32; ++i) {
      const float f = s_feats[k * 32 + i];
      akk = fmaf(f, p.cak_w[i * 32 + h], akk);
      avv = fmaf(f, p.cav_w[i * 32 + h], avv);
    }
    s_u[k * 32 + h] = akk;
    s_u[512 + k * 32 + h] = avv;
  }
  __syncthreads();

  // ---- Phase D: 8 march steps + epilogue (byte-identical to round 10) ----
  for (int s = 0; s <= 8; ++s) {
    float rv0 = 0.f, rv1 = 0.f, rv2 = 0.f;
    {  // secA: hv[16][128] -> s_hidb (bf16)
      const int k = t >> 4, d0 = (t & 15) * 8;
      float c0, c1, c2;
      if (s < 8) {
        c0 = s_coords[k * 3 + 0] - s_op[0];
        c1 = s_coords[k * 3 + 1] - s_op[1];
        c2 = s_coords[k * 3 + 2] - s_op[2];
      } else {
        const float rd = s_reld[k];
        c0 = s_relv[k * 3 + 0] * rd; c1 = s_relv[k * 3 + 1] * rd; c2 = s_relv[k * 3 + 2] * rd;
      }
#pragma unroll
      for (int x = 0; x < 8; x += 2) {
        const int d = d0 + x;
        const float h0v = fmaxf(fmaf(c0, p.cap_w1[d],
                           fmaf(c1, p.cap_w1[128 + d],
                           fmaf(c2, p.cap_w1[256 + d], p.cap_b1[d]))), 0.f);
        const float h1v = fmaxf(fmaf(c0, p.cap_w1[d + 1],
                           fmaf(c1, p.cap_w1[128 + d + 1],
                           fmaf(c2, p.cap_w1[256 + d + 1], p.cap_b1[d + 1]))), 0.f);
        ((unsigned*)s_hidb)[(k * HSTR + d) >> 1] = pack2(h0v, h1v);
      }
    }
    if (t < 64) {  // wave0: rel/o_ld + shuffle feat_mlp chain -> s_qq
      const int h = l & 31;
      if (s < 8 && l < 16) {
        const float r0 = s_coords[l * 3 + 0] - s_op[0];
        const float r1 = s_coords[l * 3 + 1] - s_op[1];
        const float r2 = s_coords[l * 3 + 2] - s_op[2];
        const float rd = sqrtf(r0 * r0 + r1 * r1 + r2 * r2);
        const float inv = 1.f / rd;
        rv0 = r0 * inv; rv1 = r1 * inv; rv2 = r2 * inv;
        s_reld[l] = rd;
        s_relv[l * 3 + 0] = rv0; s_relv[l * 3 + 1] = rv1; s_relv[l * 3 + 2] = rv2;
        p.o_ld[b * 128 + s * 16 + l] = rd;
      }
      float opc0, opc1, opc2;
      if (s < 8) {
        const float cum = s_cum;
        opc0 = s_qry[0] * cum; opc1 = s_qry[1] * cum; opc2 = s_qry[2] * cum;
      } else {
        opc0 = s_op[0]; opc1 = s_op[1]; opc2 = s_op[2];
      }
      float v1 = fmaxf(fmaf(opc0, p.fw1[h],
                    fmaf(opc1, p.fw1[32 + h],
                    fmaf(opc2, p.fw1[64 + h], p.fb1[h]))), 0.f);
      float a = p.fb2[h];
      for (int i2 = 0; i2 < 32; ++i2) a = fmaf(__shfl(v1, i2, 32), p.fw2[i2 * 32 + h], a);
      const float v2 = fmaxf(a, 0.f);
      a = p.fb3[h];
      for (int i2 = 0; i2 < 32; ++i2) a = fmaf(__shfl(v2, i2, 32), p.fw3[i2 * 32 + h], a);
      const float opf = a;
      a = p.caq_b[h];
      for (int i2 = 0; i2 < 32; ++i2) a = fmaf(__shfl(opf, i2, 32), p.caq_w[i2 * 32 + h], a);
      if (l < 32) s_qq[h] = a;
    }
    __syncthreads();
    if (w < 2) {  // secB: pe[16][32] = hv @ cap_w2 + b2; fused ain -> s_simb
      const int n = w * 16 + ln16;
      const float bias = p.cap_b2[n];
      f32x4 acc = {bias, bias, bias, bias};
#pragma unroll
      for (int kk = 0; kk < 4; ++kk) {
        const u16x8 a = *(const u16x8*)&s_hidb[ln16 * HSTR + kk * 32 + k0];
        const u16x8 bb = *(const u16x8*)&s_wTA[n * HSTR + kk * 32 + k0];
        MFMA(acc, a, bb);
      }
      MFMA_FENCE(acc);
#pragma unroll
      for (int r2 = 0; r2 < 4; ++r2) {
        const int row = kg * 4 + r2;
        const float pe = acc[r2];
        s_rpe[row * 33 + n] = pe;
        s_simb[row * BSTR + n] = f2b(s_qq[n] - s_u[row * 32 + n] + pe);
      }
    }
    __syncthreads();
    {  // secC: hid[16][128] = relu(ain @ caa_w1 + b1) -> s_hidb
      const u16x8 a = *(const u16x8*)&s_simb[ln16 * BSTR + k0];
#pragma unroll
      for (int j2 = 0; j2 < 2; ++j2) {
        const int n = (w * 2 + j2) * 16 + ln16;
        const u16x8 bb = *(const u16x8*)&s_wTB[n * BSTR + k0];
        const float bias = p.caa_b1[n];
        f32x4 acc = {bias, bias, bias, bias};
        MFMA(acc, a, bb);
        MFMA_FENCE(acc);
#pragma unroll
        for (int r2 = 0; r2 < 4; ++r2)
          s_hidb[(kg * 4 + r2) * HSTR + n] = f2b(fmaxf(acc[r2], 0.f));
      }
    }
    __syncthreads();
    if (w < 2) {  // secD: sim[16][32] = hid @ caa_w2 + b2 -> s_sim (fp32)
      const int n = w * 16 + ln16;
      const float bias = p.caa_b2[n];
      f32x4 acc = {bias, bias, bias, bias};
#pragma unroll
      for (int kk = 0; kk < 4; ++kk) {
        const u16x8 a = *(const u16x8*)&s_hidb[ln16 * HSTR + kk * 32 + k0];
        const u16x8 bb = *(const u16x8*)&s_wTC[n * HSTR + kk * 32 + k0];
        MFMA(acc, a, bb);
      }
      MFMA_FENCE(acc);
#pragma unroll
      for (int r2 = 0; r2 < 4; ++r2) s_sim[(kg * 4 + r2) * 33 + n] = acc[r2];
    }
    __syncthreads();
    if (t < 64) {  // secE: softmax + ca + (im chain | ep chain) on wave0
      const int h = l & 31;
      float mx = -1e30f;
#pragma unroll
      for (int k = 0; k < 16; ++k) mx = fmaxf(mx, s_sim[k * 33 + h]);
      float sum = 0.f, o = 0.f;
#pragma unroll
      for (int k = 0; k < 16; ++k) {
        const float e = __expf(s_sim[k * 33 + h] - mx);
        sum += e;
        o = fmaf(e, s_u[512 + k * 32 + h] + s_rpe[k * 33 + h], o);
      }
      const float ca = o / sum;
      if (s < 8) {
        float a = p.im_b1[h];
        for (int i2 = 0; i2 < 32; ++i2) a = fmaf(__shfl(ca, i2, 32), p.im_w1[i2 * 32 + h], a);
        const float m1 = fmaxf(a, 0.f);
        a = p.im_b2[h];
        for (int i2 = 0; i2 < 32; ++i2) a = fmaf(__shfl(m1, i2, 32), p.im_w2[i2 * 32 + h], a);
        const float m2 = fmaxf(a, 0.f);
        float p0 = m2 * p.im_w3[h * 3 + 0];
        float p1 = m2 * p.im_w3[h * 3 + 1];
        float p2 = m2 * p.im_w3[h * 3 + 2];
#pragma unroll
        for (int m = 1; m < 32; m <<= 1) {
          p0 += __shfl_xor(p0, m, 32);
          p1 += __shfl_xor(p1, m, 32);
          p2 += __shfl_xor(p2, m, 32);
        }
        p0 += p.im_b3[0]; p1 += p.im_b3[1]; p2 += p.im_b3[2];
        const float step = sqrtf(p0 * p0 + p1 * p1 + p2 * p2);
        const float cum = s_cum;
        const float opc0 = s_qry[0] * cum, opc1 = s_qry[1] * cum, opc2 = s_qry[2] * cum;
        const float inv = 1.f / step;
        const float tg0 = p0 * inv, tg1 = p1 * inv, tg2 = p2 * inv;
        if (l == 0) {
          p.o_ms[b * 8 + s] = step;
          p.o_ip[(b * 8 + s) * 3 + 0] = opc0 + p0;
          s_op[0] = opc0 + s_qry[0] * step;
        } else if (l == 1) {
          p.o_ip[(b * 8 + s) * 3 + 1] = opc1 + p1;
          s_op[1] = opc1 + s_qry[1] * step;
        } else if (l == 2) {
          p.o_ip[(b * 8 + s) * 3 + 2] = opc2 + p2;
          s_op[2] = opc2 + s_qry[2] * step;
        } else if (l == 3) {
          s_cum = cum + step;
        }
        if (l < 16) {
          p.o_cs[b * 128 + s * 16 + l] = tg0 * rv0 + tg1 * rv1 + tg2 * rv2;
        }
      } else {
        float a = p.ep_b1[h];
        for (int i2 = 0; i2 < 32; ++i2) a = fmaf(__shfl(ca, i2, 32), p.ep_w1[i2 * 32 + h], a);
        a = fmaf(s_qry[0], p.ep_w1[1024 + h], a);
        a = fmaf(s_qry[1], p.ep_w1[1056 + h], a);
        a = fmaf(s_qry[2], p.ep_w1[1088 + h], a);
        const float e1 = fmaxf(a, 0.f);
        a = p.ep_b2[h];
        for (int i2 = 0; i2 < 32; ++i2) a = fmaf(__shfl(e1, i2, 32), p.ep_w2[i2 * 32 + h], a);
        const float e2 = fmaxf(a, 0.f);
        float pp = e2 * p.ep_w3[h];
#pragma unroll
        for (int m = 1; m < 32; m <<= 1) pp += __shfl_xor(pp, m, 32);
        if (l == 0) {
          p.o_eps[b] = pp + p.ep_b3[0];
          p.o_cum[b] = s_cum;
        }
      }
    }
    __syncthreads();
  }
}

extern "C" void kernel_launch(void* const* d_in, const int* in_sizes, int n_in,
                              void* d_out, int out_size, void* d_ws, size_t ws_size,
                              hipStream_t stream) {
  Params p;
  const float** f = (const float**)(void*)&p;
  for (int i = 0; i < 43; ++i) f[i] = (const float*)d_in[i];
  float* out = (float*)d_out;
  p.o_ld  = out;
  p.o_ms  = out + OFF_MS;
  p.o_cs  = out + OFF_CS;
  p.o_ip  = out + OFF_IP;
  p.o_cum = out + OFF_CUM;
  p.o_eps = out + OFF_EPS;
  puray_kernel<<<dim3(4096), dim3(256), 0, stream>>>(p);
}

// Round 14
// 766.141 us; speedup vs baseline: 1.7009x; 1.1268x over previous
//
#include <hip/hip_runtime.h>

// Problem constants: B=4096, K=16, H=32, HM=128, STEPS=8
#define OFF_MS  524288
#define OFF_CS  557056
#define OFF_IP  1081344
#define OFF_CUM 1179648
#define OFF_EPS 1183744

#define HSTR 136   // padded bf16 row stride (272B -> 2-way banks)
#define BSTR 40    // padded bf16 row stride (80B)

// d_ws layout (u16): bf16 weights transposed to [n][k]
#define WA_PTP 0        // ptp_w2T [32][128]
#define WB_PTA 4096     // pta_w1T [128][32]
#define WC_PTA 8192     // pta_w2T [32][128]
#define WA_CAP 12288    // cap_w2T [32][128]
#define WB_CAA 16384    // caa_w1T [128][32]
#define WC_CAA 20480    // caa_w2T [32][128]

struct Params {
  const float *knn, *query, *fw1, *fb1, *fw2, *fb2, *fw3, *fb3, *qkv_w,
    *ptp_w1, *ptp_b1, *ptp_w2, *ptp_b2, *pta_w1, *pta_b1, *pta_w2, *pta_b2,
    *caq_w, *caq_b, *cak_w, *cak_b, *cav_w, *cav_b,
    *cap_w1, *cap_b1, *cap_w2, *cap_b2, *caa_w1, *caa_b1, *caa_w2, *caa_b2,
    *im_w1, *im_b1, *im_w2, *im_b2, *im_w3, *im_b3,
    *ep_w1, *ep_b1, *ep_w2, *ep_b2, *ep_w3, *ep_b3;
  float *o_ld, *o_ms, *o_cs, *o_ip, *o_cum, *o_eps;
};
static_assert(sizeof(Params) == 49 * sizeof(void*), "Params layout");

typedef float f32x4 __attribute__((ext_vector_type(4)));
typedef unsigned short u16x8 __attribute__((ext_vector_type(8)));

__device__ __forceinline__ unsigned short f2b(float x) {  // fp32->bf16 RNE
  unsigned u = __float_as_uint(x);
  u += 0x7fffu + ((u >> 16) & 1u);
  return (unsigned short)(u >> 16);
}
__device__ __forceinline__ unsigned pack2(float lo, float hi) {
  return (unsigned)f2b(lo) | ((unsigned)f2b(hi) << 16);
}

#define MFMA(acc, a, bb) \
  asm volatile("s_nop 2\n\tv_mfma_f32_16x16x32_bf16 %0, %1, %2, %0" \
               : "+v"(acc) : "v"(a), "v"(bb))
#define MFMA_FENCE(acc) asm volatile("s_nop 7\n\ts_nop 7" : "+v"(acc))

// Prep: transpose+convert the 6 MFMA weight matrices into d_ws (once/launch).
__global__ void prep_kernel(Params p, unsigned short* ws) {
  const int t = blockIdx.x * 256 + threadIdx.x;  // 0..4095
  const int n = t >> 7, k = t & 127;
  ws[WA_PTP + t] = f2b(p.ptp_w2[k * 32 + n]);
  ws[WC_PTA + t] = f2b(p.pta_w2[k * 32 + n]);
  ws[WA_CAP + t] = f2b(p.cap_w2[k * 32 + n]);
  ws[WC_CAA + t] = f2b(p.caa_w2[k * 32 + n]);
  const int n2 = t >> 5, k2 = t & 31;
  ws[WB_PTA + t] = f2b(p.pta_w1[k2 * 128 + n2]);
  ws[WB_CAA + t] = f2b(p.caa_w1[k2 * 128 + n2]);
}

// hv -> A-fragment helper: lane = row ln16, k = DBASE..DBASE+7
#define MK_AF(AF, W1, B1, DBASE) { \
  union { u16x8 v; unsigned u[4]; } cv_; \
  cv_.u[0] = pack2( \
    fmaxf(fmaf(c0, (W1)[(DBASE)+0], fmaf(c1, (W1)[128+(DBASE)+0], fmaf(c2, (W1)[256+(DBASE)+0], (B1)[(DBASE)+0]))), 0.f), \
    fmaxf(fmaf(c0, (W1)[(DBASE)+1], fmaf(c1, (W1)[128+(DBASE)+1], fmaf(c2, (W1)[256+(DBASE)+1], (B1)[(DBASE)+1]))), 0.f)); \
  cv_.u[1] = pack2( \
    fmaxf(fmaf(c0, (W1)[(DBASE)+2], fmaf(c1, (W1)[128+(DBASE)+2], fmaf(c2, (W1)[256+(DBASE)+2], (B1)[(DBASE)+2]))), 0.f), \
    fmaxf(fmaf(c0, (W1)[(DBASE)+3], fmaf(c1, (W1)[128+(DBASE)+3], fmaf(c2, (W1)[256+(DBASE)+3], (B1)[(DBASE)+3]))), 0.f)); \
  cv_.u[2] = pack2( \
    fmaxf(fmaf(c0, (W1)[(DBASE)+4], fmaf(c1, (W1)[128+(DBASE)+4], fmaf(c2, (W1)[256+(DBASE)+4], (B1)[(DBASE)+4]))), 0.f), \
    fmaxf(fmaf(c0, (W1)[(DBASE)+5], fmaf(c1, (W1)[128+(DBASE)+5], fmaf(c2, (W1)[256+(DBASE)+5], (B1)[(DBASE)+5]))), 0.f)); \
  cv_.u[3] = pack2( \
    fmaxf(fmaf(c0, (W1)[(DBASE)+6], fmaf(c1, (W1)[128+(DBASE)+6], fmaf(c2, (W1)[256+(DBASE)+6], (B1)[(DBASE)+6]))), 0.f), \
    fmaxf(fmaf(c0, (W1)[(DBASE)+7], fmaf(c1, (W1)[128+(DBASE)+7], fmaf(c2, (W1)[256+(DBASE)+7], (B1)[(DBASE)+7]))), 0.f)); \
  AF = cv_.v; }

// WAVE-PER-BATCH: 64-thread blocks, one batch each, ZERO barriers in the
// main flow (wave-ordered LDS). Weights come from d_ws (prep kernel) as
// global bf16 [n][k] B-fragments; A-fragments computed directly in regs.
// (64,2): VGPR cap 128 (proven no-spill budget), 8 independent waves/CU.
__launch_bounds__(64, 2)
__global__ void puray_kernel(Params p, const unsigned short* ws) {
  const int b = blockIdx.x;
  const int l = threadIdx.x;
  const int ln16 = l & 15, kg = l >> 4, k0 = kg * 8;

  __shared__ __align__(16) unsigned short s_hidb[16 * HSTR];
  __shared__ __align__(16) unsigned short s_simb[16 * BSTR];
  __shared__ float s_feats[512], s_v[512];
  __shared__ float s_u[1024];    // A: h1|h2 ; B/C: q|k ; D: kk|vvb
  __shared__ float s_coords[48], s_relv[48], s_reld[16];
  __shared__ float s_qry[3], s_op[3], s_qq[32], s_ca[32];
  __shared__ float s_cum;

  if (l < 48) s_coords[l] = p.knn[b * 48 + l];
  else if (l < 51) s_qry[l - 48] = p.query[b * 3 + (l - 48)];
  else if (l == 51) s_cum = 0.f;
  else if (l < 55) s_op[l - 52] = 0.f;
  __syncthreads();

  // ---- Phase A: feats (h1 -> s_u[0:512], h2 -> s_u[512:1024]) ----
  for (int m = 0; m < 8; ++m) {
    const int idx = l + 64 * m, pp = idx >> 5, jj = idx & 31;
    float a = p.fb1[jj];
    for (int c = 0; c < 3; ++c) a = fmaf(s_coords[pp * 3 + c], p.fw1[c * 32 + jj], a);
    s_u[idx] = fmaxf(a, 0.f);
  }
  for (int m = 0; m < 8; ++m) {
    const int idx = l + 64 * m, pp = idx >> 5, jj = idx & 31;
    float a = p.fb2[jj];
    for (int i = 0; i < 32; ++i) a = fmaf(s_u[pp * 32 + i], p.fw2[i * 32 + jj], a);
    s_u[512 + idx] = fmaxf(a, 0.f);
  }
  for (int m = 0; m < 8; ++m) {
    const int idx = l + 64 * m, pp = idx >> 5, jj = idx & 31;
    float a = p.fb3[jj];
    for (int i = 0; i < 32; ++i) a = fmaf(s_u[512 + pp * 32 + i], p.fw3[i * 32 + jj], a);
    s_feats[idx] = a;
  }
  // ---- Phase B: qkv -> s_u (q|k) + s_v ----
  for (int m = 0; m < 24; ++m) {
    const int idx = l + 64 * m, pp = idx / 96, o = idx % 96;
    float a = 0.f;
    for (int i = 0; i < 32; ++i) a = fmaf(s_feats[pp * 32 + i], p.qkv_w[i * 96 + o], a);
    if (o < 32) s_u[pp * 32 + o] = a;
    else if (o < 64) s_u[512 + pp * 32 + o - 32] = a;
    else s_v[pp * 32 + o - 64] = a;
  }

  // ---- Phase C: one i-row at a time, all within the wave ----
  for (int i = 0; i < 16; ++i) {
    const float c0 = s_coords[i * 3 + 0] - s_coords[ln16 * 3 + 0];
    const float c1 = s_coords[i * 3 + 1] - s_coords[ln16 * 3 + 1];
    const float c2 = s_coords[i * 3 + 2] - s_coords[ln16 * 3 + 2];
    u16x8 af0, af1, af2, af3;
    MK_AF(af0, p.ptp_w1, p.ptp_b1, 0 * 32 + k0);
    MK_AF(af1, p.ptp_w1, p.ptp_b1, 1 * 32 + k0);
    MK_AF(af2, p.ptp_w1, p.ptp_b1, 2 * 32 + k0);
    MK_AF(af3, p.ptp_w1, p.ptp_b1, 3 * 32 + k0);
    f32x4 rpe0, rpe1;
    {  // G1 nb=0
      const int n = ln16;
      const float bias = p.ptp_b2[n];
      f32x4 acc = {bias, bias, bias, bias};
      MFMA(acc, af0, *(const u16x8*)&ws[WA_PTP + n * 128 + 0 * 32 + k0]);
      MFMA(acc, af1, *(const u16x8*)&ws[WA_PTP + n * 128 + 1 * 32 + k0]);
      MFMA(acc, af2, *(const u16x8*)&ws[WA_PTP + n * 128 + 2 * 32 + k0]);
      MFMA(acc, af3, *(const u16x8*)&ws[WA_PTP + n * 128 + 3 * 32 + k0]);
      MFMA_FENCE(acc);
      rpe0 = acc;
#pragma unroll
      for (int r2 = 0; r2 < 4; ++r2) {
        const int j = kg * 4 + r2;
        s_simb[j * BSTR + n] = f2b(s_u[i * 32 + n] - s_u[512 + j * 32 + n] + acc[r2]);
      }
    }
    {  // G1 nb=1
      const int n = 16 + ln16;
      const float bias = p.ptp_b2[n];
      f32x4 acc = {bias, bias, bias, bias};
      MFMA(acc, af0, *(const u16x8*)&ws[WA_PTP + n * 128 + 0 * 32 + k0]);
      MFMA(acc, af1, *(const u16x8*)&ws[WA_PTP + n * 128 + 1 * 32 + k0]);
      MFMA(acc, af2, *(const u16x8*)&ws[WA_PTP + n * 128 + 2 * 32 + k0]);
      MFMA(acc, af3, *(const u16x8*)&ws[WA_PTP + n * 128 + 3 * 32 + k0]);
      MFMA_FENCE(acc);
      rpe1 = acc;
#pragma unroll
      for (int r2 = 0; r2 < 4; ++r2) {
        const int j = kg * 4 + r2;
        s_simb[j * BSTR + n] = f2b(s_u[i * 32 + n] - s_u[512 + j * 32 + n] + acc[r2]);
      }
    }
    {  // G2: hid[16][128] = relu(simin @ pta_w1 + b1)
      const u16x8 a2 = *(const u16x8*)&s_simb[ln16 * BSTR + k0];
#pragma unroll
      for (int j2 = 0; j2 < 8; ++j2) {
        const int n = j2 * 16 + ln16;
        const float bias = p.pta_b1[n];
        f32x4 acc = {bias, bias, bias, bias};
        MFMA(acc, a2, *(const u16x8*)&ws[WB_PTA + n * 32 + k0]);
        MFMA_FENCE(acc);
#pragma unroll
        for (int r2 = 0; r2 < 4; ++r2)
          s_hidb[(kg * 4 + r2) * HSTR + n] = f2b(fmaxf(acc[r2], 0.f));
      }
    }
    // G3 + fused softmax -> feats[i]
#pragma unroll
    for (int nb = 0; nb < 2; ++nb) {
      const int n = nb * 16 + ln16;
      const float bias = p.pta_b2[n];
      f32x4 acc = {bias, bias, bias, bias};
#pragma unroll
      for (int kk = 0; kk < 4; ++kk) {
        const u16x8 a3 = *(const u16x8*)&s_hidb[ln16 * HSTR + kk * 32 + k0];
        MFMA(acc, a3, *(const u16x8*)&ws[WC_PTA + n * 128 + kk * 32 + k0]);
      }
      MFMA_FENCE(acc);
      const f32x4 rp = nb ? rpe1 : rpe0;
      float mx = fmaxf(fmaxf(acc[0], acc[1]), fmaxf(acc[2], acc[3]));
      mx = fmaxf(mx, __shfl_xor(mx, 16));
      mx = fmaxf(mx, __shfl_xor(mx, 32));
      float sum = 0.f, o = 0.f;
#pragma unroll
      for (int r2 = 0; r2 < 4; ++r2) {
        const int j = kg * 4 + r2;
        const float e = __expf(acc[r2] - mx);
        sum += e;
        o = fmaf(e, s_v[j * 32 + n] + rp[r2], o);
      }
      sum += __shfl_xor(sum, 16); o += __shfl_xor(o, 16);
      sum += __shfl_xor(sum, 32); o += __shfl_xor(o, 32);
      if (kg == 0) s_feats[i * 32 + n] = o / sum;
    }
  }

  // ---- kk / vvb (overwrite q|k in s_u) ----
  for (int m = 0; m < 8; ++m) {
    const int idx = l + 64 * m, k = idx >> 5, h = idx & 31;
    float akk = p.cak_b[h], avv = p.cav_b[h];
    for (int i = 0; i < 32; ++i) {
      const float f = s_feats[k * 32 + i];
      akk = fmaf(f, p.cak_w[i * 32 + h], akk);
      avv = fmaf(f, p.cav_w[i * 32 + h], avv);
    }
    s_u[k * 32 + h] = akk;
    s_u[512 + k * 32 + h] = avv;
  }

  // ---- Phase D: 8 march steps + epilogue, all within the wave ----
  for (int s = 0; s <= 8; ++s) {
    float rv0 = 0.f, rv1 = 0.f, rv2 = 0.f;
    if (s < 8 && l < 16) {  // rel + o_ld
      const float r0 = s_coords[l * 3 + 0] - s_op[0];
      const float r1 = s_coords[l * 3 + 1] - s_op[1];
      const float r2 = s_coords[l * 3 + 2] - s_op[2];
      const float rd = sqrtf(r0 * r0 + r1 * r1 + r2 * r2);
      const float inv = 1.f / rd;
      rv0 = r0 * inv; rv1 = r1 * inv; rv2 = r2 * inv;
      s_reld[l] = rd;
      s_relv[l * 3 + 0] = rv0; s_relv[l * 3 + 1] = rv1; s_relv[l * 3 + 2] = rv2;
      p.o_ld[b * 128 + s * 16 + l] = rd;
    }
    // secA: pe-hidden A-fragments (row = ln16)
    float c0, c1, c2;
    if (s < 8) {
      c0 = s_coords[ln16 * 3 + 0] - s_op[0];
      c1 = s_coords[ln16 * 3 + 1] - s_op[1];
      c2 = s_coords[ln16 * 3 + 2] - s_op[2];
    } else {
      const float rd = s_reld[ln16];
      c0 = s_relv[ln16 * 3 + 0] * rd; c1 = s_relv[ln16 * 3 + 1] * rd; c2 = s_relv[ln16 * 3 + 2] * rd;
    }
    u16x8 af0, af1, af2, af3;
    MK_AF(af0, p.cap_w1, p.cap_b1, 0 * 32 + k0);
    MK_AF(af1, p.cap_w1, p.cap_b1, 1 * 32 + k0);
    MK_AF(af2, p.cap_w1, p.cap_b1, 2 * 32 + k0);
    MK_AF(af3, p.cap_w1, p.cap_b1, 3 * 32 + k0);
    {  // qq chain (all lanes, width-32 shuffles; halves duplicate)
      const int h = l & 31;
      float opc0, opc1, opc2;
      if (s < 8) {
        const float cum = s_cum;
        opc0 = s_qry[0] * cum; opc1 = s_qry[1] * cum; opc2 = s_qry[2] * cum;
      } else {
        opc0 = s_op[0]; opc1 = s_op[1]; opc2 = s_op[2];
      }
      float v1 = fmaxf(fmaf(opc0, p.fw1[h],
                    fmaf(opc1, p.fw1[32 + h],
                    fmaf(opc2, p.fw1[64 + h], p.fb1[h]))), 0.f);
      float a = p.fb2[h];
      for (int i2 = 0; i2 < 32; ++i2) a = fmaf(__shfl(v1, i2, 32), p.fw2[i2 * 32 + h], a);
      const float v2 = fmaxf(a, 0.f);
      a = p.fb3[h];
      for (int i2 = 0; i2 < 32; ++i2) a = fmaf(__shfl(v2, i2, 32), p.fw3[i2 * 32 + h], a);
      const float opf = a;
      a = p.caq_b[h];
      for (int i2 = 0; i2 < 32; ++i2) a = fmaf(__shfl(opf, i2, 32), p.caq_w[i2 * 32 + h], a);
      if (l < 32) s_qq[h] = a;
    }
    f32x4 pe0, pe1;
    {  // secB nb=0
      const int n = ln16;
      const float bias = p.cap_b2[n];
      f32x4 acc = {bias, bias, bias, bias};
      MFMA(acc, af0, *(const u16x8*)&ws[WA_CAP + n * 128 + 0 * 32 + k0]);
      MFMA(acc, af1, *(const u16x8*)&ws[WA_CAP + n * 128 + 1 * 32 + k0]);
      MFMA(acc, af2, *(const u16x8*)&ws[WA_CAP + n * 128 + 2 * 32 + k0]);
      MFMA(acc, af3, *(const u16x8*)&ws[WA_CAP + n * 128 + 3 * 32 + k0]);
      MFMA_FENCE(acc);
      pe0 = acc;
#pragma unroll
      for (int r2 = 0; r2 < 4; ++r2) {
        const int row = kg * 4 + r2;
        s_simb[row * BSTR + n] = f2b(s_qq[n] - s_u[row * 32 + n] + acc[r2]);
      }
    }
    {  // secB nb=1
      const int n = 16 + ln16;
      const float bias = p.cap_b2[n];
      f32x4 acc = {bias, bias, bias, bias};
      MFMA(acc, af0, *(const u16x8*)&ws[WA_CAP + n * 128 + 0 * 32 + k0]);
      MFMA(acc, af1, *(const u16x8*)&ws[WA_CAP + n * 128 + 1 * 32 + k0]);
      MFMA(acc, af2, *(const u16x8*)&ws[WA_CAP + n * 128 + 2 * 32 + k0]);
      MFMA(acc, af3, *(const u16x8*)&ws[WA_CAP + n * 128 + 3 * 32 + k0]);
      MFMA_FENCE(acc);
      pe1 = acc;
#pragma unroll
      for (int r2 = 0; r2 < 4; ++r2) {
        const int row = kg * 4 + r2;
        s_simb[row * BSTR + n] = f2b(s_qq[n] - s_u[row * 32 + n] + acc[r2]);
      }
    }
    {  // secC: hid = relu(ain @ caa_w1 + b1)
      const u16x8 a2 = *(const u16x8*)&s_simb[ln16 * BSTR + k0];
#pragma unroll
      for (int j2 = 0; j2 < 8; ++j2) {
        const int n = j2 * 16 + ln16;
        const float bias = p.caa_b1[n];
        f32x4 acc = {bias, bias, bias, bias};
        MFMA(acc, a2, *(const u16x8*)&ws[WB_CAA + n * 32 + k0]);
        MFMA_FENCE(acc);
#pragma unroll
        for (int r2 = 0; r2 < 4; ++r2)
          s_hidb[(kg * 4 + r2) * HSTR + n] = f2b(fmaxf(acc[r2], 0.f));
      }
    }
    // secD + in-register softmax -> ca0/ca1 (all lanes hold result)
    float ca0 = 0.f, ca1 = 0.f;
#pragma unroll
    for (int nb = 0; nb < 2; ++nb) {
      const int n = nb * 16 + ln16;
      const float bias = p.caa_b2[n];
      f32x4 acc = {bias, bias, bias, bias};
#pragma unroll
      for (int kk = 0; kk < 4; ++kk) {
        const u16x8 a3 = *(const u16x8*)&s_hidb[ln16 * HSTR + kk * 32 + k0];
        MFMA(acc, a3, *(const u16x8*)&ws[WC_CAA + n * 128 + kk * 32 + k0]);
      }
      MFMA_FENCE(acc);
      const f32x4 rp = nb ? pe1 : pe0;
      float mx = fmaxf(fmaxf(acc[0], acc[1]), fmaxf(acc[2], acc[3]));
      mx = fmaxf(mx, __shfl_xor(mx, 16));
      mx = fmaxf(mx, __shfl_xor(mx, 32));
      float sum = 0.f, o = 0.f;
#pragma unroll
      for (int r2 = 0; r2 < 4; ++r2) {
        const int row = kg * 4 + r2;
        const float e = __expf(acc[r2] - mx);
        sum += e;
        o = fmaf(e, s_u[512 + row * 32 + n] + rp[r2], o);
      }
      sum += __shfl_xor(sum, 16); o += __shfl_xor(o, 16);
      sum += __shfl_xor(sum, 32); o += __shfl_xor(o, 32);
      if (nb == 0) ca0 = o / sum; else ca1 = o / sum;
    }
    if (kg == 0) { s_ca[ln16] = ca0; s_ca[16 + ln16] = ca1; }
    {  // im / ep chain (width-32; halves duplicate; writes guarded)
      const int h = l & 31;
      const float cav = s_ca[h];
      if (s < 8) {
        float a = p.im_b1[h];
        for (int i2 = 0; i2 < 32; ++i2) a = fmaf(__shfl(cav, i2, 32), p.im_w1[i2 * 32 + h], a);
        const float m1 = fmaxf(a, 0.f);
        a = p.im_b2[h];
        for (int i2 = 0; i2 < 32; ++i2) a = fmaf(__shfl(m1, i2, 32), p.im_w2[i2 * 32 + h], a);
        const float m2 = fmaxf(a, 0.f);
        float p0 = m2 * p.im_w3[h * 3 + 0];
        float p1 = m2 * p.im_w3[h * 3 + 1];
        float p2 = m2 * p.im_w3[h * 3 + 2];
#pragma unroll
        for (int m = 1; m < 32; m <<= 1) {
          p0 += __shfl_xor(p0, m, 32);
          p1 += __shfl_xor(p1, m, 32);
          p2 += __shfl_xor(p2, m, 32);
        }
        p0 += p.im_b3[0]; p1 += p.im_b3[1]; p2 += p.im_b3[2];
        const float step = sqrtf(p0 * p0 + p1 * p1 + p2 * p2);
        const float cum = s_cum;
        const float opc0 = s_qry[0] * cum, opc1 = s_qry[1] * cum, opc2 = s_qry[2] * cum;
        const float inv = 1.f / step;
        const float tg0 = p0 * inv, tg1 = p1 * inv, tg2 = p2 * inv;
        if (l == 0) {
          p.o_ms[b * 8 + s] = step;
          p.o_ip[(b * 8 + s) * 3 + 0] = opc0 + p0;
          s_op[0] = opc0 + s_qry[0] * step;
        } else if (l == 1) {
          p.o_ip[(b * 8 + s) * 3 + 1] = opc1 + p1;
          s_op[1] = opc1 + s_qry[1] * step;
        } else if (l == 2) {
          p.o_ip[(b * 8 + s) * 3 + 2] = opc2 + p2;
          s_op[2] = opc2 + s_qry[2] * step;
        } else if (l == 3) {
          s_cum = cum + step;
        }
        if (l < 16) {
          p.o_cs[b * 128 + s * 16 + l] = tg0 * rv0 + tg1 * rv1 + tg2 * rv2;
        }
      } else {
        float a = p.ep_b1[h];
        for (int i2 = 0; i2 < 32; ++i2) a = fmaf(__shfl(cav, i2, 32), p.ep_w1[i2 * 32 + h], a);
        a = fmaf(s_qry[0], p.ep_w1[1024 + h], a);
        a = fmaf(s_qry[1], p.ep_w1[1056 + h], a);
        a = fmaf(s_qry[2], p.ep_w1[1088 + h], a);
        const float e1 = fmaxf(a, 0.f);
        a = p.ep_b2[h];
        for (int i2 = 0; i2 < 32; ++i2) a = fmaf(__shfl(e1, i2, 32), p.ep_w2[i2 * 32 + h], a);
        const float e2 = fmaxf(a, 0.f);
        float pp = e2 * p.ep_w3[h];
#pragma unroll
        for (int m = 1; m < 32; m <<= 1) pp += __shfl_xor(pp, m, 32);
        if (l == 0) {
          p.o_eps[b] = pp + p.ep_b3[0];
          p.o_cum[b] = s_cum;
        }
      }
    }
  }
}

extern "C" void kernel_launch(void* const* d_in, const int* in_sizes, int n_in,
                              void* d_out, int out_size, void* d_ws, size_t ws_size,
                              hipStream_t stream) {
  Params p;
  const float** f = (const float**)(void*)&p;
  for (int i = 0; i < 43; ++i) f[i] = (const float*)d_in[i];
  float* out = (float*)d_out;
  p.o_ld  = out;
  p.o_ms  = out + OFF_MS;
  p.o_cs  = out + OFF_CS;
  p.o_ip  = out + OFF_IP;
  p.o_cum = out + OFF_CUM;
  p.o_eps = out + OFF_EPS;
  unsigned short* ws = (unsigned short*)d_ws;
  prep_kernel<<<dim3(16), dim3(256), 0, stream>>>(p, ws);
  puray_kernel<<<dim3(4096), dim3(64), 0, stream>>>(p, ws);
}

// Round 15
// 662.670 us; speedup vs baseline: 1.9665x; 1.1561x over previous
//
#include <hip/hip_runtime.h>

// Problem constants: B=4096, K=16, H=32, HM=128, STEPS=8
#define OFF_MS  524288
#define OFF_CS  557056
#define OFF_IP  1081344
#define OFF_CUM 1179648
#define OFF_EPS 1183744

#define HSTR 136   // padded bf16 row stride (272B -> 2-way banks)
#define BSTR 40    // padded bf16 row stride (80B)

// d_ws layout (u16): bf16 weights transposed to [n][k]
#define WA_PTP 0        // ptp_w2T [32][128]
#define WB_PTA 4096     // pta_w1T [128][32]
#define WC_PTA 8192     // pta_w2T [32][128]
#define WA_CAP 12288    // cap_w2T [32][128]
#define WB_CAA 16384    // caa_w1T [128][32]
#define WC_CAA 20480    // caa_w2T [32][128]

struct Params {
  const float *knn, *query, *fw1, *fb1, *fw2, *fb2, *fw3, *fb3, *qkv_w,
    *ptp_w1, *ptp_b1, *ptp_w2, *ptp_b2, *pta_w1, *pta_b1, *pta_w2, *pta_b2,
    *caq_w, *caq_b, *cak_w, *cak_b, *cav_w, *cav_b,
    *cap_w1, *cap_b1, *cap_w2, *cap_b2, *caa_w1, *caa_b1, *caa_w2, *caa_b2,
    *im_w1, *im_b1, *im_w2, *im_b2, *im_w3, *im_b3,
    *ep_w1, *ep_b1, *ep_w2, *ep_b2, *ep_w3, *ep_b3;
  float *o_ld, *o_ms, *o_cs, *o_ip, *o_cum, *o_eps;
};
static_assert(sizeof(Params) == 49 * sizeof(void*), "Params layout");

typedef float f32x4 __attribute__((ext_vector_type(4)));
typedef unsigned short u16x8 __attribute__((ext_vector_type(8)));

__device__ __forceinline__ unsigned short f2b(float x) {  // fp32->bf16 RNE
  unsigned u = __float_as_uint(x);
  u += 0x7fffu + ((u >> 16) & 1u);
  return (unsigned short)(u >> 16);
}
__device__ __forceinline__ unsigned pack2(float lo, float hi) {
  return (unsigned)f2b(lo) | ((unsigned)f2b(hi) << 16);
}

#define MFMA(acc, a, bb) \
  asm volatile("s_nop 2\n\tv_mfma_f32_16x16x32_bf16 %0, %1, %2, %0" \
               : "+v"(acc) : "v"(a), "v"(bb))
#define MFMA_FENCE(acc) asm volatile("s_nop 7\n\ts_nop 7" : "+v"(acc))

// Prep: transpose+convert the 6 MFMA weight matrices into d_ws (once/launch).
__global__ void prep_kernel(Params p, unsigned short* ws) {
  const int t = blockIdx.x * 256 + threadIdx.x;  // 0..4095
  const int n = t >> 7, k = t & 127;
  ws[WA_PTP + t] = f2b(p.ptp_w2[k * 32 + n]);
  ws[WC_PTA + t] = f2b(p.pta_w2[k * 32 + n]);
  ws[WA_CAP + t] = f2b(p.cap_w2[k * 32 + n]);
  ws[WC_CAA + t] = f2b(p.caa_w2[k * 32 + n]);
  const int n2 = t >> 5, k2 = t & 31;
  ws[WB_PTA + t] = f2b(p.pta_w1[k2 * 128 + n2]);
  ws[WB_CAA + t] = f2b(p.caa_w1[k2 * 128 + n2]);
}

// hv -> A-fragment helper: lane = row ln16, k = DBASE..DBASE+7
#define MK_AF(AF, W1, B1, DBASE) { \
  union { u16x8 v; unsigned u[4]; } cv_; \
  cv_.u[0] = pack2( \
    fmaxf(fmaf(c0, (W1)[(DBASE)+0], fmaf(c1, (W1)[128+(DBASE)+0], fmaf(c2, (W1)[256+(DBASE)+0], (B1)[(DBASE)+0]))), 0.f), \
    fmaxf(fmaf(c0, (W1)[(DBASE)+1], fmaf(c1, (W1)[128+(DBASE)+1], fmaf(c2, (W1)[256+(DBASE)+1], (B1)[(DBASE)+1]))), 0.f)); \
  cv_.u[1] = pack2( \
    fmaxf(fmaf(c0, (W1)[(DBASE)+2], fmaf(c1, (W1)[128+(DBASE)+2], fmaf(c2, (W1)[256+(DBASE)+2], (B1)[(DBASE)+2]))), 0.f), \
    fmaxf(fmaf(c0, (W1)[(DBASE)+3], fmaf(c1, (W1)[128+(DBASE)+3], fmaf(c2, (W1)[256+(DBASE)+3], (B1)[(DBASE)+3]))), 0.f)); \
  cv_.u[2] = pack2( \
    fmaxf(fmaf(c0, (W1)[(DBASE)+4], fmaf(c1, (W1)[128+(DBASE)+4], fmaf(c2, (W1)[256+(DBASE)+4], (B1)[(DBASE)+4]))), 0.f), \
    fmaxf(fmaf(c0, (W1)[(DBASE)+5], fmaf(c1, (W1)[128+(DBASE)+5], fmaf(c2, (W1)[256+(DBASE)+5], (B1)[(DBASE)+5]))), 0.f)); \
  cv_.u[3] = pack2( \
    fmaxf(fmaf(c0, (W1)[(DBASE)+6], fmaf(c1, (W1)[128+(DBASE)+6], fmaf(c2, (W1)[256+(DBASE)+6], (B1)[(DBASE)+6]))), 0.f), \
    fmaxf(fmaf(c0, (W1)[(DBASE)+7], fmaf(c1, (W1)[128+(DBASE)+7], fmaf(c2, (W1)[256+(DBASE)+7], (B1)[(DBASE)+7]))), 0.f)); \
  AF = cv_.v; }

// WAVE-PER-BATCH (round 14) + anti-hoist pointer obscuring. Round 14 hit
// VGPR cap + 212MB/254MB scratch spill because the compiler hoisted the
// loop-invariant weight loads (MK_AF's 128 w1 floats/lane, ws B-fragments)
// out of the i/s loops. Empty asm "+s" on the base pointers each iteration
// forces reload (L1-resident tables) -> pressure below 128 cap, no spill.
__launch_bounds__(64, 2)
__global__ void puray_kernel(Params p, const unsigned short* ws) {
  const int b = blockIdx.x;
  const int l = threadIdx.x;
  const int ln16 = l & 15, kg = l >> 4, k0 = kg * 8;

  __shared__ __align__(16) unsigned short s_hidb[16 * HSTR];
  __shared__ __align__(16) unsigned short s_simb[16 * BSTR];
  __shared__ float s_feats[512], s_v[512];
  __shared__ float s_u[1024];    // A: h1|h2 ; B/C: q|k ; D: kk|vvb
  __shared__ float s_coords[48], s_relv[48], s_reld[16];
  __shared__ float s_qry[3], s_op[3], s_qq[32], s_ca[32];
  __shared__ float s_cum;

  if (l < 48) s_coords[l] = p.knn[b * 48 + l];
  else if (l < 51) s_qry[l - 48] = p.query[b * 3 + (l - 48)];
  else if (l == 51) s_cum = 0.f;
  else if (l < 55) s_op[l - 52] = 0.f;
  __syncthreads();

  // ---- Phase A: feats (h1 -> s_u[0:512], h2 -> s_u[512:1024]) ----
  for (int m = 0; m < 8; ++m) {
    const int idx = l + 64 * m, pp = idx >> 5, jj = idx & 31;
    float a = p.fb1[jj];
    for (int c = 0; c < 3; ++c) a = fmaf(s_coords[pp * 3 + c], p.fw1[c * 32 + jj], a);
    s_u[idx] = fmaxf(a, 0.f);
  }
  for (int m = 0; m < 8; ++m) {
    const int idx = l + 64 * m, pp = idx >> 5, jj = idx & 31;
    float a = p.fb2[jj];
    for (int i = 0; i < 32; ++i) a = fmaf(s_u[pp * 32 + i], p.fw2[i * 32 + jj], a);
    s_u[512 + idx] = fmaxf(a, 0.f);
  }
  for (int m = 0; m < 8; ++m) {
    const int idx = l + 64 * m, pp = idx >> 5, jj = idx & 31;
    float a = p.fb3[jj];
    for (int i = 0; i < 32; ++i) a = fmaf(s_u[512 + pp * 32 + i], p.fw3[i * 32 + jj], a);
    s_feats[idx] = a;
  }
  // ---- Phase B: qkv -> s_u (q|k) + s_v ----
  for (int m = 0; m < 24; ++m) {
    const int idx = l + 64 * m, pp = idx / 96, o = idx % 96;
    float a = 0.f;
    for (int i = 0; i < 32; ++i) a = fmaf(s_feats[pp * 32 + i], p.qkv_w[i * 96 + o], a);
    if (o < 32) s_u[pp * 32 + o] = a;
    else if (o < 64) s_u[512 + pp * 32 + o - 32] = a;
    else s_v[pp * 32 + o - 64] = a;
  }

  // ---- Phase C: one i-row at a time, all within the wave ----
  {
    const float* w1c = p.ptp_w1;
    const float* b1c = p.ptp_b1;
    const float* b2c = p.ptp_b2;
    const float* bh1 = p.pta_b1;
    const float* bh2 = p.pta_b2;
    const unsigned short* wsc = ws;
    for (int i = 0; i < 16; ++i) {
      asm volatile("" : "+s"(w1c), "+s"(b1c), "+s"(b2c), "+s"(bh1), "+s"(bh2), "+s"(wsc));
      const float c0 = s_coords[i * 3 + 0] - s_coords[ln16 * 3 + 0];
      const float c1 = s_coords[i * 3 + 1] - s_coords[ln16 * 3 + 1];
      const float c2 = s_coords[i * 3 + 2] - s_coords[ln16 * 3 + 2];
      u16x8 af0, af1, af2, af3;
      MK_AF(af0, w1c, b1c, 0 * 32 + k0);
      MK_AF(af1, w1c, b1c, 1 * 32 + k0);
      MK_AF(af2, w1c, b1c, 2 * 32 + k0);
      MK_AF(af3, w1c, b1c, 3 * 32 + k0);
      f32x4 rpe0, rpe1;
      {  // G1 nb=0
        const int n = ln16;
        const float bias = b2c[n];
        f32x4 acc = {bias, bias, bias, bias};
        MFMA(acc, af0, *(const u16x8*)&wsc[WA_PTP + n * 128 + 0 * 32 + k0]);
        MFMA(acc, af1, *(const u16x8*)&wsc[WA_PTP + n * 128 + 1 * 32 + k0]);
        MFMA(acc, af2, *(const u16x8*)&wsc[WA_PTP + n * 128 + 2 * 32 + k0]);
        MFMA(acc, af3, *(const u16x8*)&wsc[WA_PTP + n * 128 + 3 * 32 + k0]);
        MFMA_FENCE(acc);
        rpe0 = acc;
#pragma unroll
        for (int r2 = 0; r2 < 4; ++r2) {
          const int j = kg * 4 + r2;
          s_simb[j * BSTR + n] = f2b(s_u[i * 32 + n] - s_u[512 + j * 32 + n] + acc[r2]);
        }
      }
      {  // G1 nb=1
        const int n = 16 + ln16;
        const float bias = b2c[n];
        f32x4 acc = {bias, bias, bias, bias};
        MFMA(acc, af0, *(const u16x8*)&wsc[WA_PTP + n * 128 + 0 * 32 + k0]);
        MFMA(acc, af1, *(const u16x8*)&wsc[WA_PTP + n * 128 + 1 * 32 + k0]);
        MFMA(acc, af2, *(const u16x8*)&wsc[WA_PTP + n * 128 + 2 * 32 + k0]);
        MFMA(acc, af3, *(const u16x8*)&wsc[WA_PTP + n * 128 + 3 * 32 + k0]);
        MFMA_FENCE(acc);
        rpe1 = acc;
#pragma unroll
        for (int r2 = 0; r2 < 4; ++r2) {
          const int j = kg * 4 + r2;
          s_simb[j * BSTR + n] = f2b(s_u[i * 32 + n] - s_u[512 + j * 32 + n] + acc[r2]);
        }
      }
      {  // G2: hid[16][128] = relu(simin @ pta_w1 + b1)
        const u16x8 a2 = *(const u16x8*)&s_simb[ln16 * BSTR + k0];
#pragma unroll
        for (int j2 = 0; j2 < 8; ++j2) {
          const int n = j2 * 16 + ln16;
          const float bias = bh1[n];
          f32x4 acc = {bias, bias, bias, bias};
          MFMA(acc, a2, *(const u16x8*)&wsc[WB_PTA + n * 32 + k0]);
          MFMA_FENCE(acc);
#pragma unroll
          for (int r2 = 0; r2 < 4; ++r2)
            s_hidb[(kg * 4 + r2) * HSTR + n] = f2b(fmaxf(acc[r2], 0.f));
        }
      }
      // G3 + fused softmax -> feats[i]
#pragma unroll
      for (int nb = 0; nb < 2; ++nb) {
        const int n = nb * 16 + ln16;
        const float bias = bh2[n];
        f32x4 acc = {bias, bias, bias, bias};
#pragma unroll
        for (int kk = 0; kk < 4; ++kk) {
          const u16x8 a3 = *(const u16x8*)&s_hidb[ln16 * HSTR + kk * 32 + k0];
          MFMA(acc, a3, *(const u16x8*)&wsc[WC_PTA + n * 128 + kk * 32 + k0]);
        }
        MFMA_FENCE(acc);
        const f32x4 rp = nb ? rpe1 : rpe0;
        float mx = fmaxf(fmaxf(acc[0], acc[1]), fmaxf(acc[2], acc[3]));
        mx = fmaxf(mx, __shfl_xor(mx, 16));
        mx = fmaxf(mx, __shfl_xor(mx, 32));
        float sum = 0.f, o = 0.f;
#pragma unroll
        for (int r2 = 0; r2 < 4; ++r2) {
          const int j = kg * 4 + r2;
          const float e = __expf(acc[r2] - mx);
          sum += e;
          o = fmaf(e, s_v[j * 32 + n] + rp[r2], o);
        }
        sum += __shfl_xor(sum, 16); o += __shfl_xor(o, 16);
        sum += __shfl_xor(sum, 32); o += __shfl_xor(o, 32);
        if (kg == 0) s_feats[i * 32 + n] = o / sum;
      }
    }
  }

  // ---- kk / vvb (overwrite q|k in s_u) ----
  for (int m = 0; m < 8; ++m) {
    const int idx = l + 64 * m, k = idx >> 5, h = idx & 31;
    float akk = p.cak_b[h], avv = p.cav_b[h];
    for (int i = 0; i < 32; ++i) {
      const float f = s_feats[k * 32 + i];
      akk = fmaf(f, p.cak_w[i * 32 + h], akk);
      avv = fmaf(f, p.cav_w[i * 32 + h], avv);
    }
    s_u[k * 32 + h] = akk;
    s_u[512 + k * 32 + h] = avv;
  }

  // ---- Phase D: 8 march steps + epilogue, all within the wave ----
  {
    const float* w1d = p.cap_w1;
    const float* b1d = p.cap_b1;
    const float* b2d = p.cap_b2;
    const float* bc1 = p.caa_b1;
    const float* bc2 = p.caa_b2;
    const float* fw1 = p.fw1; const float* fw2 = p.fw2; const float* fw3 = p.fw3;
    const float* cqw = p.caq_w;
    const float* iw1 = p.im_w1; const float* iw2 = p.im_w2; const float* iw3 = p.im_w3;
    const unsigned short* wsd = ws;
    for (int s = 0; s <= 8; ++s) {
      asm volatile("" : "+s"(w1d), "+s"(b1d), "+s"(b2d), "+s"(bc1), "+s"(bc2), "+s"(wsd));
      asm volatile("" : "+s"(fw1), "+s"(fw2), "+s"(fw3), "+s"(cqw), "+s"(iw1), "+s"(iw2), "+s"(iw3));
      float rv0 = 0.f, rv1 = 0.f, rv2 = 0.f;
      if (s < 8 && l < 16) {  // rel + o_ld
        const float r0 = s_coords[l * 3 + 0] - s_op[0];
        const float r1 = s_coords[l * 3 + 1] - s_op[1];
        const float r2 = s_coords[l * 3 + 2] - s_op[2];
        const float rd = sqrtf(r0 * r0 + r1 * r1 + r2 * r2);
        const float inv = 1.f / rd;
        rv0 = r0 * inv; rv1 = r1 * inv; rv2 = r2 * inv;
        s_reld[l] = rd;
        s_relv[l * 3 + 0] = rv0; s_relv[l * 3 + 1] = rv1; s_relv[l * 3 + 2] = rv2;
        p.o_ld[b * 128 + s * 16 + l] = rd;
      }
      // secA: pe-hidden A-fragments (row = ln16)
      float c0, c1, c2;
      if (s < 8) {
        c0 = s_coords[ln16 * 3 + 0] - s_op[0];
        c1 = s_coords[ln16 * 3 + 1] - s_op[1];
        c2 = s_coords[ln16 * 3 + 2] - s_op[2];
      } else {
        const float rd = s_reld[ln16];
        c0 = s_relv[ln16 * 3 + 0] * rd; c1 = s_relv[ln16 * 3 + 1] * rd; c2 = s_relv[ln16 * 3 + 2] * rd;
      }
      u16x8 af0, af1, af2, af3;
      MK_AF(af0, w1d, b1d, 0 * 32 + k0);
      MK_AF(af1, w1d, b1d, 1 * 32 + k0);
      MK_AF(af2, w1d, b1d, 2 * 32 + k0);
      MK_AF(af3, w1d, b1d, 3 * 32 + k0);
      {  // qq chain (all lanes, width-32 shuffles; halves duplicate)
        const int h = l & 31;
        float opc0, opc1, opc2;
        if (s < 8) {
          const float cum = s_cum;
          opc0 = s_qry[0] * cum; opc1 = s_qry[1] * cum; opc2 = s_qry[2] * cum;
        } else {
          opc0 = s_op[0]; opc1 = s_op[1]; opc2 = s_op[2];
        }
        float v1 = fmaxf(fmaf(opc0, fw1[h],
                      fmaf(opc1, fw1[32 + h],
                      fmaf(opc2, fw1[64 + h], p.fb1[h]))), 0.f);
        float a = p.fb2[h];
        for (int i2 = 0; i2 < 32; ++i2) a = fmaf(__shfl(v1, i2, 32), fw2[i2 * 32 + h], a);
        const float v2 = fmaxf(a, 0.f);
        a = p.fb3[h];
        for (int i2 = 0; i2 < 32; ++i2) a = fmaf(__shfl(v2, i2, 32), fw3[i2 * 32 + h], a);
        const float opf = a;
        a = p.caq_b[h];
        for (int i2 = 0; i2 < 32; ++i2) a = fmaf(__shfl(opf, i2, 32), cqw[i2 * 32 + h], a);
        if (l < 32) s_qq[h] = a;
      }
      f32x4 pe0, pe1;
      {  // secB nb=0
        const int n = ln16;
        const float bias = b2d[n];
        f32x4 acc = {bias, bias, bias, bias};
        MFMA(acc, af0, *(const u16x8*)&wsd[WA_CAP + n * 128 + 0 * 32 + k0]);
        MFMA(acc, af1, *(const u16x8*)&wsd[WA_CAP + n * 128 + 1 * 32 + k0]);
        MFMA(acc, af2, *(const u16x8*)&wsd[WA_CAP + n * 128 + 2 * 32 + k0]);
        MFMA(acc, af3, *(const u16x8*)&wsd[WA_CAP + n * 128 + 3 * 32 + k0]);
        MFMA_FENCE(acc);
        pe0 = acc;
#pragma unroll
        for (int r2 = 0; r2 < 4; ++r2) {
          const int row = kg * 4 + r2;
          s_simb[row * BSTR + n] = f2b(s_qq[n] - s_u[row * 32 + n] + acc[r2]);
        }
      }
      {  // secB nb=1
        const int n = 16 + ln16;
        const float bias = b2d[n];
        f32x4 acc = {bias, bias, bias, bias};
        MFMA(acc, af0, *(const u16x8*)&wsd[WA_CAP + n * 128 + 0 * 32 + k0]);
        MFMA(acc, af1, *(const u16x8*)&wsd[WA_CAP + n * 128 + 1 * 32 + k0]);
        MFMA(acc, af2, *(const u16x8*)&wsd[WA_CAP + n * 128 + 2 * 32 + k0]);
        MFMA(acc, af3, *(const u16x8*)&wsd[WA_CAP + n * 128 + 3 * 32 + k0]);
        MFMA_FENCE(acc);
        pe1 = acc;
#pragma unroll
        for (int r2 = 0; r2 < 4; ++r2) {
          const int row = kg * 4 + r2;
          s_simb[row * BSTR + n] = f2b(s_qq[n] - s_u[row * 32 + n] + acc[r2]);
        }
      }
      {  // secC: hid = relu(ain @ caa_w1 + b1)
        const u16x8 a2 = *(const u16x8*)&s_simb[ln16 * BSTR + k0];
#pragma unroll
        for (int j2 = 0; j2 < 8; ++j2) {
          const int n = j2 * 16 + ln16;
          const float bias = bc1[n];
          f32x4 acc = {bias, bias, bias, bias};
          MFMA(acc, a2, *(const u16x8*)&wsd[WB_CAA + n * 32 + k0]);
          MFMA_FENCE(acc);
#pragma unroll
          for (int r2 = 0; r2 < 4; ++r2)
            s_hidb[(kg * 4 + r2) * HSTR + n] = f2b(fmaxf(acc[r2], 0.f));
        }
      }
      // secD + in-register softmax -> ca0/ca1
      float ca0 = 0.f, ca1 = 0.f;
#pragma unroll
      for (int nb = 0; nb < 2; ++nb) {
        const int n = nb * 16 + ln16;
        const float bias = bc2[n];
        f32x4 acc = {bias, bias, bias, bias};
#pragma unroll
        for (int kk = 0; kk < 4; ++kk) {
          const u16x8 a3 = *(const u16x8*)&s_hidb[ln16 * HSTR + kk * 32 + k0];
          MFMA(acc, a3, *(const u16x8*)&wsd[WC_CAA + n * 128 + kk * 32 + k0]);
        }
        MFMA_FENCE(acc);
        const f32x4 rp = nb ? pe1 : pe0;
        float mx = fmaxf(fmaxf(acc[0], acc[1]), fmaxf(acc[2], acc[3]));
        mx = fmaxf(mx, __shfl_xor(mx, 16));
        mx = fmaxf(mx, __shfl_xor(mx, 32));
        float sum = 0.f, o = 0.f;
#pragma unroll
        for (int r2 = 0; r2 < 4; ++r2) {
          const int row = kg * 4 + r2;
          const float e = __expf(acc[r2] - mx);
          sum += e;
          o = fmaf(e, s_u[512 + row * 32 + n] + rp[r2], o);
        }
        sum += __shfl_xor(sum, 16); o += __shfl_xor(o, 16);
        sum += __shfl_xor(sum, 32); o += __shfl_xor(o, 32);
        if (nb == 0) ca0 = o / sum; else ca1 = o / sum;
      }
      if (kg == 0) { s_ca[ln16] = ca0; s_ca[16 + ln16] = ca1; }
      {  // im / ep chain (width-32; halves duplicate; writes guarded)
        const int h = l & 31;
        const float cav = s_ca[h];
        if (s < 8) {
          float a = p.im_b1[h];
          for (int i2 = 0; i2 < 32; ++i2) a = fmaf(__shfl(cav, i2, 32), iw1[i2 * 32 + h], a);
          const float m1 = fmaxf(a, 0.f);
          a = p.im_b2[h];
          for (int i2 = 0; i2 < 32; ++i2) a = fmaf(__shfl(m1, i2, 32), iw2[i2 * 32 + h], a);
          const float m2 = fmaxf(a, 0.f);
          float p0 = m2 * iw3[h * 3 + 0];
          float p1 = m2 * iw3[h * 3 + 1];
          float p2 = m2 * iw3[h * 3 + 2];
#pragma unroll
          for (int m = 1; m < 32; m <<= 1) {
            p0 += __shfl_xor(p0, m, 32);
            p1 += __shfl_xor(p1, m, 32);
            p2 += __shfl_xor(p2, m, 32);
          }
          p0 += p.im_b3[0]; p1 += p.im_b3[1]; p2 += p.im_b3[2];
          const float step = sqrtf(p0 * p0 + p1 * p1 + p2 * p2);
          const float cum = s_cum;
          const float opc0 = s_qry[0] * cum, opc1 = s_qry[1] * cum, opc2 = s_qry[2] * cum;
          const float inv = 1.f / step;
          const float tg0 = p0 * inv, tg1 = p1 * inv, tg2 = p2 * inv;
          if (l == 0) {
            p.o_ms[b * 8 + s] = step;
            p.o_ip[(b * 8 + s) * 3 + 0] = opc0 + p0;
            s_op[0] = opc0 + s_qry[0] * step;
          } else if (l == 1) {
            p.o_ip[(b * 8 + s) * 3 + 1] = opc1 + p1;
            s_op[1] = opc1 + s_qry[1] * step;
          } else if (l == 2) {
            p.o_ip[(b * 8 + s) * 3 + 2] = opc2 + p2;
            s_op[2] = opc2 + s_qry[2] * step;
          } else if (l == 3) {
            s_cum = cum + step;
          }
          if (l < 16) {
            p.o_cs[b * 128 + s * 16 + l] = tg0 * rv0 + tg1 * rv1 + tg2 * rv2;
          }
        } else {
          float a = p.ep_b1[h];
          for (int i2 = 0; i2 < 32; ++i2) a = fmaf(__shfl(cav, i2, 32), p.ep_w1[i2 * 32 + h], a);
          a = fmaf(s_qry[0], p.ep_w1[1024 + h], a);
          a = fmaf(s_qry[1], p.ep_w1[1056 + h], a);
          a = fmaf(s_qry[2], p.ep_w1[1088 + h], a);
          const float e1 = fmaxf(a, 0.f);
          a = p.ep_b2[h];
          for (int i2 = 0; i2 < 32; ++i2) a = fmaf(__shfl(e1, i2, 32), p.ep_w2[i2 * 32 + h], a);
          const float e2 = fmaxf(a, 0.f);
          float pp = e2 * p.ep_w3[h];
#pragma unroll
          for (int m = 1; m < 32; m <<= 1) pp += __shfl_xor(pp, m, 32);
          if (l == 0) {
            p.o_eps[b] = pp + p.ep_b3[0];
            p.o_cum[b] = s_cum;
          }
        }
      }
    }
  }
}

extern "C" void kernel_launch(void* const* d_in, const int* in_sizes, int n_in,
                              void* d_out, int out_size, void* d_ws, size_t ws_size,
                              hipStream_t stream) {
  Params p;
  const float** f = (const float**)(void*)&p;
  for (int i = 0; i < 43; ++i) f[i] = (const float*)d_in[i];
  float* out = (float*)d_out;
  p.o_ld  = out;
  p.o_ms  = out + OFF_MS;
  p.o_cs  = out + OFF_CS;
  p.o_ip  = out + OFF_IP;
  p.o_cum = out + OFF_CUM;
  p.o_eps = out + OFF_EPS;
  unsigned short* ws = (unsigned short*)d_ws;
  prep_kernel<<<dim3(16), dim3(256), 0, stream>>>(p, ws);
  puray_kernel<<<dim3(4096), dim3(64), 0, stream>>>(p, ws);
}

// Round 16
// 452.569 us; speedup vs baseline: 2.8794x; 1.4642x over previous
//
#include <hip/hip_runtime.h>

// Problem constants: B=4096, K=16, H=32, HM=128, STEPS=8
#define OFF_MS  524288
#define OFF_CS  557056
#define OFF_IP  1081344
#define OFF_CUM 1179648
#define OFF_EPS 1183744

#define HSTR 136   // padded bf16 row stride (272B -> 2-way banks)
#define BSTR 40    // padded bf16 row stride (80B)

// d_ws layout (u16): bf16 weights transposed to [n][k]
#define WA_PTP 0        // ptp_w2T [32][128]
#define WB_PTA 4096     // pta_w1T [128][32]
#define WC_PTA 8192     // pta_w2T [32][128]
#define WA_CAP 12288    // cap_w2T [32][128]
#define WB_CAA 16384    // caa_w1T [128][32]
#define WC_CAA 20480    // caa_w2T [32][128]

struct Params {
  const float *knn, *query, *fw1, *fb1, *fw2, *fb2, *fw3, *fb3, *qkv_w,
    *ptp_w1, *ptp_b1, *ptp_w2, *ptp_b2, *pta_w1, *pta_b1, *pta_w2, *pta_b2,
    *caq_w, *caq_b, *cak_w, *cak_b, *cav_w, *cav_b,
    *cap_w1, *cap_b1, *cap_w2, *cap_b2, *caa_w1, *caa_b1, *caa_w2, *caa_b2,
    *im_w1, *im_b1, *im_w2, *im_b2, *im_w3, *im_b3,
    *ep_w1, *ep_b1, *ep_w2, *ep_b2, *ep_w3, *ep_b3;
  float *o_ld, *o_ms, *o_cs, *o_ip, *o_cum, *o_eps;
};
static_assert(sizeof(Params) == 49 * sizeof(void*), "Params layout");

typedef float f32x4 __attribute__((ext_vector_type(4)));
typedef unsigned short u16x8 __attribute__((ext_vector_type(8)));

__device__ __forceinline__ unsigned short f2b(float x) {  // fp32->bf16 RNE
  unsigned u = __float_as_uint(x);
  u += 0x7fffu + ((u >> 16) & 1u);
  return (unsigned short)(u >> 16);
}
__device__ __forceinline__ unsigned pack2(float lo, float hi) {
  return (unsigned)f2b(lo) | ((unsigned)f2b(hi) << 16);
}

#define MFMA(acc, a, bb) \
  asm volatile("s_nop 2\n\tv_mfma_f32_16x16x32_bf16 %0, %1, %2, %0" \
               : "+v"(acc) : "v"(a), "v"(bb))
#define MFMA_FENCE(acc) asm volatile("s_nop 7\n\ts_nop 7" : "+v"(acc))

// Prep: transpose+convert the 6 MFMA weight matrices into d_ws (once/launch).
__global__ void prep_kernel(Params p, unsigned short* ws) {
  const int t = blockIdx.x * 256 + threadIdx.x;  // 0..4095
  const int n = t >> 7, k = t & 127;
  ws[WA_PTP + t] = f2b(p.ptp_w2[k * 32 + n]);
  ws[WC_PTA + t] = f2b(p.pta_w2[k * 32 + n]);
  ws[WA_CAP + t] = f2b(p.cap_w2[k * 32 + n]);
  ws[WC_CAA + t] = f2b(p.caa_w2[k * 32 + n]);
  const int n2 = t >> 5, k2 = t & 31;
  ws[WB_PTA + t] = f2b(p.pta_w1[k2 * 128 + n2]);
  ws[WB_CAA + t] = f2b(p.caa_w1[k2 * 128 + n2]);
}

// WAVE-PER-BATCH (rounds 14/15) + LDS-staged A-operands. Round 15 still
// spilled 403MB because MK_AF kept 4 A-fragments (16 VGPR) live across MFMA
// sections while feeding them with 128-load bursts. Fix = rounds 9/10's
// proven pattern: hv computed 2-values-at-a-time into s_hvb (tiny live
// state), fragments ds_read_b128'd AT the MFMA (no cross-section ranges).
// Same-wave LDS handoff needs no barrier. Anti-hoist "+s" asm retained.
__launch_bounds__(64, 2)
__global__ void puray_kernel(Params p, const unsigned short* ws) {
  const int b = blockIdx.x;
  const int l = threadIdx.x;
  const int ln16 = l & 15, kg = l >> 4, k0 = kg * 8;

  __shared__ __align__(16) unsigned short s_hvb[16 * HSTR];   // hv A-operand
  __shared__ __align__(16) unsigned short s_hidb[16 * HSTR];  // G2/secC out
  __shared__ __align__(16) unsigned short s_simb[16 * BSTR];
  __shared__ float s_feats[512], s_v[512];
  __shared__ float s_u[1024];    // A: h1|h2 ; B/C: q|k ; D: kk|vvb
  __shared__ float s_coords[48], s_relv[48], s_reld[16];
  __shared__ float s_qry[3], s_op[3], s_qq[32], s_ca[32];
  __shared__ float s_cum;

  if (l < 48) s_coords[l] = p.knn[b * 48 + l];
  else if (l < 51) s_qry[l - 48] = p.query[b * 3 + (l - 48)];
  else if (l == 51) s_cum = 0.f;
  else if (l < 55) s_op[l - 52] = 0.f;
  __syncthreads();

  // ---- Phase A: feats (h1 -> s_u[0:512], h2 -> s_u[512:1024]) ----
  for (int m = 0; m < 8; ++m) {
    const int idx = l + 64 * m, pp = idx >> 5, jj = idx & 31;
    float a = p.fb1[jj];
    for (int c = 0; c < 3; ++c) a = fmaf(s_coords[pp * 3 + c], p.fw1[c * 32 + jj], a);
    s_u[idx] = fmaxf(a, 0.f);
  }
  for (int m = 0; m < 8; ++m) {
    const int idx = l + 64 * m, pp = idx >> 5, jj = idx & 31;
    float a = p.fb2[jj];
    for (int i = 0; i < 32; ++i) a = fmaf(s_u[pp * 32 + i], p.fw2[i * 32 + jj], a);
    s_u[512 + idx] = fmaxf(a, 0.f);
  }
  for (int m = 0; m < 8; ++m) {
    const int idx = l + 64 * m, pp = idx >> 5, jj = idx & 31;
    float a = p.fb3[jj];
    for (int i = 0; i < 32; ++i) a = fmaf(s_u[512 + pp * 32 + i], p.fw3[i * 32 + jj], a);
    s_feats[idx] = a;
  }
  // ---- Phase B: qkv -> s_u (q|k) + s_v ----
  for (int m = 0; m < 24; ++m) {
    const int idx = l + 64 * m, pp = idx / 96, o = idx % 96;
    float a = 0.f;
    for (int i = 0; i < 32; ++i) a = fmaf(s_feats[pp * 32 + i], p.qkv_w[i * 96 + o], a);
    if (o < 32) s_u[pp * 32 + o] = a;
    else if (o < 64) s_u[512 + pp * 32 + o - 32] = a;
    else s_v[pp * 32 + o - 64] = a;
  }

  // ---- Phase C: one i-row at a time, all within the wave ----
  {
    const float* w1c = p.ptp_w1;
    const float* b1c = p.ptp_b1;
    const float* b2c = p.ptp_b2;
    const float* bh1 = p.pta_b1;
    const float* bh2 = p.pta_b2;
    const unsigned short* wsc = ws;
    for (int i = 0; i < 16; ++i) {
      asm volatile("" : "+s"(w1c), "+s"(b1c), "+s"(b2c), "+s"(bh1), "+s"(bh2), "+s"(wsc));
      const float c0 = s_coords[i * 3 + 0] - s_coords[ln16 * 3 + 0];
      const float c1 = s_coords[i * 3 + 1] - s_coords[ln16 * 3 + 1];
      const float c2 = s_coords[i * 3 + 2] - s_coords[ln16 * 3 + 2];
      // hv -> s_hvb (row ln16, d = kg*32 .. kg*32+31; 2 live values only)
      for (int x = 0; x < 32; x += 2) {
        const int d = kg * 32 + x;
        const float h0v = fmaxf(fmaf(c0, w1c[d],
                           fmaf(c1, w1c[128 + d],
                           fmaf(c2, w1c[256 + d], b1c[d]))), 0.f);
        const float h1v = fmaxf(fmaf(c0, w1c[d + 1],
                           fmaf(c1, w1c[128 + d + 1],
                           fmaf(c2, w1c[256 + d + 1], b1c[d + 1]))), 0.f);
        ((unsigned*)s_hvb)[(ln16 * HSTR + d) >> 1] = pack2(h0v, h1v);
      }
      f32x4 rpe0, rpe1;
      {  // G1 nb=0: rpe = hv @ ptp_w2 + b2 (A from LDS)
        const int n = ln16;
        const float bias = b2c[n];
        f32x4 acc = {bias, bias, bias, bias};
#pragma unroll
        for (int kk = 0; kk < 4; ++kk) {
          const u16x8 a = *(const u16x8*)&s_hvb[ln16 * HSTR + kk * 32 + k0];
          MFMA(acc, a, *(const u16x8*)&wsc[WA_PTP + n * 128 + kk * 32 + k0]);
        }
        MFMA_FENCE(acc);
        rpe0 = acc;
#pragma unroll
        for (int r2 = 0; r2 < 4; ++r2) {
          const int j = kg * 4 + r2;
          s_simb[j * BSTR + n] = f2b(s_u[i * 32 + n] - s_u[512 + j * 32 + n] + acc[r2]);
        }
      }
      {  // G1 nb=1
        const int n = 16 + ln16;
        const float bias = b2c[n];
        f32x4 acc = {bias, bias, bias, bias};
#pragma unroll
        for (int kk = 0; kk < 4; ++kk) {
          const u16x8 a = *(const u16x8*)&s_hvb[ln16 * HSTR + kk * 32 + k0];
          MFMA(acc, a, *(const u16x8*)&wsc[WA_PTP + n * 128 + kk * 32 + k0]);
        }
        MFMA_FENCE(acc);
        rpe1 = acc;
#pragma unroll
        for (int r2 = 0; r2 < 4; ++r2) {
          const int j = kg * 4 + r2;
          s_simb[j * BSTR + n] = f2b(s_u[i * 32 + n] - s_u[512 + j * 32 + n] + acc[r2]);
        }
      }
      {  // G2: hid[16][128] = relu(simin @ pta_w1 + b1)
        const u16x8 a2 = *(const u16x8*)&s_simb[ln16 * BSTR + k0];
#pragma unroll
        for (int j2 = 0; j2 < 8; ++j2) {
          const int n = j2 * 16 + ln16;
          const float bias = bh1[n];
          f32x4 acc = {bias, bias, bias, bias};
          MFMA(acc, a2, *(const u16x8*)&wsc[WB_PTA + n * 32 + k0]);
          MFMA_FENCE(acc);
#pragma unroll
          for (int r2 = 0; r2 < 4; ++r2)
            s_hidb[(kg * 4 + r2) * HSTR + n] = f2b(fmaxf(acc[r2], 0.f));
        }
      }
      // G3 + fused softmax -> feats[i]
#pragma unroll
      for (int nb = 0; nb < 2; ++nb) {
        const int n = nb * 16 + ln16;
        const float bias = bh2[n];
        f32x4 acc = {bias, bias, bias, bias};
#pragma unroll
        for (int kk = 0; kk < 4; ++kk) {
          const u16x8 a3 = *(const u16x8*)&s_hidb[ln16 * HSTR + kk * 32 + k0];
          MFMA(acc, a3, *(const u16x8*)&wsc[WC_PTA + n * 128 + kk * 32 + k0]);
        }
        MFMA_FENCE(acc);
        const f32x4 rp = nb ? rpe1 : rpe0;
        float mx = fmaxf(fmaxf(acc[0], acc[1]), fmaxf(acc[2], acc[3]));
        mx = fmaxf(mx, __shfl_xor(mx, 16));
        mx = fmaxf(mx, __shfl_xor(mx, 32));
        float sum = 0.f, o = 0.f;
#pragma unroll
        for (int r2 = 0; r2 < 4; ++r2) {
          const int j = kg * 4 + r2;
          const float e = __expf(acc[r2] - mx);
          sum += e;
          o = fmaf(e, s_v[j * 32 + n] + rp[r2], o);
        }
        sum += __shfl_xor(sum, 16); o += __shfl_xor(o, 16);
        sum += __shfl_xor(sum, 32); o += __shfl_xor(o, 32);
        if (kg == 0) s_feats[i * 32 + n] = o / sum;
      }
    }
  }

  // ---- kk / vvb (overwrite q|k in s_u) ----
  for (int m = 0; m < 8; ++m) {
    const int idx = l + 64 * m, k = idx >> 5, h = idx & 31;
    float akk = p.cak_b[h], avv = p.cav_b[h];
    for (int i = 0; i < 32; ++i) {
      const float f = s_feats[k * 32 + i];
      akk = fmaf(f, p.cak_w[i * 32 + h], akk);
      avv = fmaf(f, p.cav_w[i * 32 + h], avv);
    }
    s_u[k * 32 + h] = akk;
    s_u[512 + k * 32 + h] = avv;
  }

  // ---- Phase D: 8 march steps + epilogue, all within the wave ----
  {
    const float* w1d = p.cap_w1;
    const float* b1d = p.cap_b1;
    const float* b2d = p.cap_b2;
    const float* bc1 = p.caa_b1;
    const float* bc2 = p.caa_b2;
    const float* fw1 = p.fw1; const float* fw2 = p.fw2; const float* fw3 = p.fw3;
    const float* cqw = p.caq_w;
    const float* iw1 = p.im_w1; const float* iw2 = p.im_w2; const float* iw3 = p.im_w3;
    const unsigned short* wsd = ws;
    for (int s = 0; s <= 8; ++s) {
      asm volatile("" : "+s"(w1d), "+s"(b1d), "+s"(b2d), "+s"(bc1), "+s"(bc2), "+s"(wsd));
      asm volatile("" : "+s"(fw1), "+s"(fw2), "+s"(fw3), "+s"(cqw), "+s"(iw1), "+s"(iw2), "+s"(iw3));
      float rv0 = 0.f, rv1 = 0.f, rv2 = 0.f;
      if (s < 8 && l < 16) {  // rel + o_ld
        const float r0 = s_coords[l * 3 + 0] - s_op[0];
        const float r1 = s_coords[l * 3 + 1] - s_op[1];
        const float r2 = s_coords[l * 3 + 2] - s_op[2];
        const float rd = sqrtf(r0 * r0 + r1 * r1 + r2 * r2);
        const float inv = 1.f / rd;
        rv0 = r0 * inv; rv1 = r1 * inv; rv2 = r2 * inv;
        s_reld[l] = rd;
        s_relv[l * 3 + 0] = rv0; s_relv[l * 3 + 1] = rv1; s_relv[l * 3 + 2] = rv2;
        p.o_ld[b * 128 + s * 16 + l] = rd;
      }
      // secA: pe-hidden hv -> s_hvb (row ln16, d = kg*32..+31)
      {
        float c0, c1, c2;
        if (s < 8) {
          c0 = s_coords[ln16 * 3 + 0] - s_op[0];
          c1 = s_coords[ln16 * 3 + 1] - s_op[1];
          c2 = s_coords[ln16 * 3 + 2] - s_op[2];
        } else {
          const float rd = s_reld[ln16];
          c0 = s_relv[ln16 * 3 + 0] * rd; c1 = s_relv[ln16 * 3 + 1] * rd; c2 = s_relv[ln16 * 3 + 2] * rd;
        }
        for (int x = 0; x < 32; x += 2) {
          const int d = kg * 32 + x;
          const float h0v = fmaxf(fmaf(c0, w1d[d],
                             fmaf(c1, w1d[128 + d],
                             fmaf(c2, w1d[256 + d], b1d[d]))), 0.f);
          const float h1v = fmaxf(fmaf(c0, w1d[d + 1],
                             fmaf(c1, w1d[128 + d + 1],
                             fmaf(c2, w1d[256 + d + 1], b1d[d + 1]))), 0.f);
          ((unsigned*)s_hvb)[(ln16 * HSTR + d) >> 1] = pack2(h0v, h1v);
        }
      }
      {  // qq chain (all lanes, width-32 shuffles; halves duplicate)
        const int h = l & 31;
        float opc0, opc1, opc2;
        if (s < 8) {
          const float cum = s_cum;
          opc0 = s_qry[0] * cum; opc1 = s_qry[1] * cum; opc2 = s_qry[2] * cum;
        } else {
          opc0 = s_op[0]; opc1 = s_op[1]; opc2 = s_op[2];
        }
        float v1 = fmaxf(fmaf(opc0, fw1[h],
                      fmaf(opc1, fw1[32 + h],
                      fmaf(opc2, fw1[64 + h], p.fb1[h]))), 0.f);
        float a = p.fb2[h];
        for (int i2 = 0; i2 < 32; ++i2) a = fmaf(__shfl(v1, i2, 32), fw2[i2 * 32 + h], a);
        const float v2 = fmaxf(a, 0.f);
        a = p.fb3[h];
        for (int i2 = 0; i2 < 32; ++i2) a = fmaf(__shfl(v2, i2, 32), fw3[i2 * 32 + h], a);
        const float opf = a;
        a = p.caq_b[h];
        for (int i2 = 0; i2 < 32; ++i2) a = fmaf(__shfl(opf, i2, 32), cqw[i2 * 32 + h], a);
        if (l < 32) s_qq[h] = a;
      }
      f32x4 pe0, pe1;
      {  // secB nb=0: pe = hv @ cap_w2 + b2 (A from LDS)
        const int n = ln16;
        const float bias = b2d[n];
        f32x4 acc = {bias, bias, bias, bias};
#pragma unroll
        for (int kk = 0; kk < 4; ++kk) {
          const u16x8 a = *(const u16x8*)&s_hvb[ln16 * HSTR + kk * 32 + k0];
          MFMA(acc, a, *(const u16x8*)&wsd[WA_CAP + n * 128 + kk * 32 + k0]);
        }
        MFMA_FENCE(acc);
        pe0 = acc;
#pragma unroll
        for (int r2 = 0; r2 < 4; ++r2) {
          const int row = kg * 4 + r2;
          s_simb[row * BSTR + n] = f2b(s_qq[n] - s_u[row * 32 + n] + acc[r2]);
        }
      }
      {  // secB nb=1
        const int n = 16 + ln16;
        const float bias = b2d[n];
        f32x4 acc = {bias, bias, bias, bias};
#pragma unroll
        for (int kk = 0; kk < 4; ++kk) {
          const u16x8 a = *(const u16x8*)&s_hvb[ln16 * HSTR + kk * 32 + k0];
          MFMA(acc, a, *(const u16x8*)&wsd[WA_CAP + n * 128 + kk * 32 + k0]);
        }
        MFMA_FENCE(acc);
        pe1 = acc;
#pragma unroll
        for (int r2 = 0; r2 < 4; ++r2) {
          const int row = kg * 4 + r2;
          s_simb[row * BSTR + n] = f2b(s_qq[n] - s_u[row * 32 + n] + acc[r2]);
        }
      }
      {  // secC: hid = relu(ain @ caa_w1 + b1)
        const u16x8 a2 = *(const u16x8*)&s_simb[ln16 * BSTR + k0];
#pragma unroll
        for (int j2 = 0; j2 < 8; ++j2) {
          const int n = j2 * 16 + ln16;
          const float bias = bc1[n];
          f32x4 acc = {bias, bias, bias, bias};
          MFMA(acc, a2, *(const u16x8*)&wsd[WB_CAA + n * 32 + k0]);
          MFMA_FENCE(acc);
#pragma unroll
          for (int r2 = 0; r2 < 4; ++r2)
            s_hidb[(kg * 4 + r2) * HSTR + n] = f2b(fmaxf(acc[r2], 0.f));
        }
      }
      // secD + in-register softmax -> ca0/ca1
      float ca0 = 0.f, ca1 = 0.f;
#pragma unroll
      for (int nb = 0; nb < 2; ++nb) {
        const int n = nb * 16 + ln16;
        const float bias = bc2[n];
        f32x4 acc = {bias, bias, bias, bias};
#pragma unroll
        for (int kk = 0; kk < 4; ++kk) {
          const u16x8 a3 = *(const u16x8*)&s_hidb[ln16 * HSTR + kk * 32 + k0];
          MFMA(acc, a3, *(const u16x8*)&wsd[WC_CAA + n * 128 + kk * 32 + k0]);
        }
        MFMA_FENCE(acc);
        const f32x4 rp = nb ? pe1 : pe0;
        float mx = fmaxf(fmaxf(acc[0], acc[1]), fmaxf(acc[2], acc[3]));
        mx = fmaxf(mx, __shfl_xor(mx, 16));
        mx = fmaxf(mx, __shfl_xor(mx, 32));
        float sum = 0.f, o = 0.f;
#pragma unroll
        for (int r2 = 0; r2 < 4; ++r2) {
          const int row = kg * 4 + r2;
          const float e = __expf(acc[r2] - mx);
          sum += e;
          o = fmaf(e, s_u[512 + row * 32 + n] + rp[r2], o);
        }
        sum += __shfl_xor(sum, 16); o += __shfl_xor(o, 16);
        sum += __shfl_xor(sum, 32); o += __shfl_xor(o, 32);
        if (nb == 0) ca0 = o / sum; else ca1 = o / sum;
      }
      if (kg == 0) { s_ca[ln16] = ca0; s_ca[16 + ln16] = ca1; }
      {  // im / ep chain (width-32; halves duplicate; writes guarded)
        const int h = l & 31;
        const float cav = s_ca[h];
        if (s < 8) {
          float a = p.im_b1[h];
          for (int i2 = 0; i2 < 32; ++i2) a = fmaf(__shfl(cav, i2, 32), iw1[i2 * 32 + h], a);
          const float m1 = fmaxf(a, 0.f);
          a = p.im_b2[h];
          for (int i2 = 0; i2 < 32; ++i2) a = fmaf(__shfl(m1, i2, 32), iw2[i2 * 32 + h], a);
          const float m2 = fmaxf(a, 0.f);
          float p0 = m2 * iw3[h * 3 + 0];
          float p1 = m2 * iw3[h * 3 + 1];
          float p2 = m2 * iw3[h * 3 + 2];
#pragma unroll
          for (int m = 1; m < 32; m <<= 1) {
            p0 += __shfl_xor(p0, m, 32);
            p1 += __shfl_xor(p1, m, 32);
            p2 += __shfl_xor(p2, m, 32);
          }
          p0 += p.im_b3[0]; p1 += p.im_b3[1]; p2 += p.im_b3[2];
          const float step = sqrtf(p0 * p0 + p1 * p1 + p2 * p2);
          const float cum = s_cum;
          const float opc0 = s_qry[0] * cum, opc1 = s_qry[1] * cum, opc2 = s_qry[2] * cum;
          const float inv = 1.f / step;
          const float tg0 = p0 * inv, tg1 = p1 * inv, tg2 = p2 * inv;
          if (l == 0) {
            p.o_ms[b * 8 + s] = step;
            p.o_ip[(b * 8 + s) * 3 + 0] = opc0 + p0;
            s_op[0] = opc0 + s_qry[0] * step;
          } else if (l == 1) {
            p.o_ip[(b * 8 + s) * 3 + 1] = opc1 + p1;
            s_op[1] = opc1 + s_qry[1] * step;
          } else if (l == 2) {
            p.o_ip[(b * 8 + s) * 3 + 2] = opc2 + p2;
            s_op[2] = opc2 + s_qry[2] * step;
          } else if (l == 3) {
            s_cum = cum + step;
          }
          if (l < 16) {
            p.o_cs[b * 128 + s * 16 + l] = tg0 * rv0 + tg1 * rv1 + tg2 * rv2;
          }
        } else {
          float a = p.ep_b1[h];
          for (int i2 = 0; i2 < 32; ++i2) a = fmaf(__shfl(cav, i2, 32), p.ep_w1[i2 * 32 + h], a);
          a = fmaf(s_qry[0], p.ep_w1[1024 + h], a);
          a = fmaf(s_qry[1], p.ep_w1[1056 + h], a);
          a = fmaf(s_qry[2], p.ep_w1[1088 + h], a);
          const float e1 = fmaxf(a, 0.f);
          a = p.ep_b2[h];
          for (int i2 = 0; i2 < 32; ++i2) a = fmaf(__shfl(e1, i2, 32), p.ep_w2[i2 * 32 + h], a);
          const float e2 = fmaxf(a, 0.f);
          float pp = e2 * p.ep_w3[h];
#pragma unroll
          for (int m = 1; m < 32; m <<= 1) pp += __shfl_xor(pp, m, 32);
          if (l == 0) {
            p.o_eps[b] = pp + p.ep_b3[0];
            p.o_cum[b] = s_cum;
          }
        }
      }
    }
  }
}

extern "C" void kernel_launch(void* const* d_in, const int* in_sizes, int n_in,
                              void* d_out, int out_size, void* d_ws, size_t ws_size,
                              hipStream_t stream) {
  Params p;
  const float** f = (const float**)(void*)&p;
  for (int i = 0; i < 43; ++i) f[i] = (const float*)d_in[i];
  float* out = (float*)d_out;
  p.o_ld  = out;
  p.o_ms  = out + OFF_MS;
  p.o_cs  = out + OFF_CS;
  p.o_ip  = out + OFF_IP;
  p.o_cum = out + OFF_CUM;
  p.o_eps = out + OFF_EPS;
  unsigned short* ws = (unsigned short*)d_ws;
  prep_kernel<<<dim3(16), dim3(256), 0, stream>>>(p, ws);
  puray_kernel<<<dim3(4096), dim3(64), 0, stream>>>(p, ws);
}